// Round 6
// baseline (863.565 us; speedup 1.0000x reference)
//
#include <hip/hip_runtime.h>
#include <hip/hip_bf16.h>

#define NN 50000
#define EE 800000
#define DD 128

// ---------------- degree (guarded) ----------------
__global__ void k_deg(const int* __restrict__ ei, int* __restrict__ deg) {
    int e = blockIdx.x * 256 + threadIdx.x;
    if (e < EE) {
        int d = ei[EE + e];                       // dst row
        if (d >= 0 && d < NN) atomicAdd(&deg[d], 1);
    }
}

__global__ void k_dis(const int* __restrict__ deg, float* __restrict__ dis) {
    int i = blockIdx.x * 256 + threadIdx.x;
    if (i < NN) dis[i] = rsqrtf((float)deg[i] + 1.0f);  // +1 self loop; always >0
}

// ---------------- CSR build: block scan of deg -> rowptr ----------------
__global__ void k_scan_block(const int* __restrict__ deg, int* __restrict__ scanned,
                             int* __restrict__ blocksum) {
    __shared__ int lds[256];
    int t = threadIdx.x;
    int i = blockIdx.x * 256 + t;
    int v = (i < NN) ? deg[i] : 0;
    lds[t] = v;
    __syncthreads();
    for (int off = 1; off < 256; off <<= 1) {
        int add = (t >= off) ? lds[t - off] : 0;
        __syncthreads();
        lds[t] += add;
        __syncthreads();
    }
    if (i < NN) scanned[i] = lds[t];              // inclusive within block
    if (t == 255) blocksum[blockIdx.x] = lds[255];
}

__global__ void k_scan_top(const int* __restrict__ blocksum, int* __restrict__ blockoff,
                           int* __restrict__ rowptr_end, int nb) {
    __shared__ int lds[256];
    int t = threadIdx.x;
    int v = (t < nb) ? blocksum[t] : 0;
    lds[t] = v;
    __syncthreads();
    for (int off = 1; off < 256; off <<= 1) {
        int add = (t >= off) ? lds[t - off] : 0;
        __syncthreads();
        lds[t] += add;
        __syncthreads();
    }
    if (t < nb) blockoff[t] = lds[t] - v;         // exclusive
    if (t == nb - 1) *rowptr_end = lds[t];        // total valid edges -> rowptr[NN]
}

__global__ void k_scan_final(const int* __restrict__ deg, const int* __restrict__ scanned,
                             const int* __restrict__ blockoff,
                             int* __restrict__ rowptr, int* __restrict__ cursor) {
    int i = blockIdx.x * 256 + threadIdx.x;
    if (i < NN) {
        int v = scanned[i] - deg[i] + blockoff[blockIdx.x];  // global exclusive
        rowptr[i] = v;
        cursor[i] = v;
    }
}

__global__ void k_fill(const int* __restrict__ ei, int* __restrict__ cursor,
                       int* __restrict__ csr) {
    int e = blockIdx.x * 256 + threadIdx.x;
    if (e < EE) {
        int s = ei[e];
        int d = ei[EE + e];
        if ((unsigned)s < (unsigned)NN && (unsigned)d < (unsigned)NN) {
            int pos = atomicAdd(&cursor[d], 1);
            csr[pos] = s;
        }
    }
}

// ---------------- BN prep: scale/shift from col stats ----------------
__global__ void k_bnprep(const float* __restrict__ cs, const float* __restrict__ css,
                         const float* __restrict__ gamma, const float* __restrict__ beta,
                         float* __restrict__ bnsc, float* __restrict__ bnsh) {
    int d = threadIdx.x;
    const float invn = 1.f / (float)NN;
    float mean = cs[d] * invn;
    float var = css[d] * invn - mean * mean;
    float sc = gamma[d] * rsqrtf(fmaxf(var, 0.f) + 1e-5f);
    bnsc[d] = sc;
    bnsh[d] = beta[d] - mean * sc;
}

// ---------------- GEMM: OUT = pro(IN) @ W (+epilogue) ----------------
// PRO: 0=none, 1=BN+relu applied to A while staging, 2=BN only
// EPI: 0=scale rows by dis[r], 1=+bias then relu
template<int PRO, int EPI>
__global__ __launch_bounds__(256) void k_gemm(const float* __restrict__ IN,
                                              const float* __restrict__ Wg,
                                              const float* __restrict__ bias,
                                              const float* __restrict__ dis,
                                              const float* __restrict__ bnsc,
                                              const float* __restrict__ bnsh,
                                              float* __restrict__ OUT) {
    __shared__ float Alds[64][68];
    __shared__ float Wlds[64][128];
    const int tid = threadIdx.x;
    const int tx = tid & 15;
    const int ty = tid >> 4;
    const int row0 = blockIdx.x * 64;

    float acc[4][8];
#pragma unroll
    for (int i = 0; i < 4; ++i)
#pragma unroll
        for (int j = 0; j < 8; ++j) acc[i][j] = 0.f;

    for (int kc = 0; kc < 2; ++kc) {
#pragma unroll
        for (int it = 0; it < 4; ++it) {
            int idx = it * 1024 + tid * 4;
            int r = idx >> 6, k = idx & 63;
            int gr = row0 + r;
            float4 v = make_float4(0.f, 0.f, 0.f, 0.f);
            if (gr < NN) v = *(const float4*)&IN[gr * DD + kc * 64 + k];
            if (PRO) {
                float4 sc = *(const float4*)&bnsc[kc * 64 + k];
                float4 sh = *(const float4*)&bnsh[kc * 64 + k];
                v.x = fmaf(v.x, sc.x, sh.x);
                v.y = fmaf(v.y, sc.y, sh.y);
                v.z = fmaf(v.z, sc.z, sh.z);
                v.w = fmaf(v.w, sc.w, sh.w);
                if (PRO == 1) {
                    v.x = fmaxf(v.x, 0.f); v.y = fmaxf(v.y, 0.f);
                    v.z = fmaxf(v.z, 0.f); v.w = fmaxf(v.w, 0.f);
                }
            }
            *(float4*)&Alds[r][k] = v;
        }
#pragma unroll
        for (int it = 0; it < 8; ++it) {
            int idx = it * 1024 + tid * 4;
            int k = idx >> 7, c = idx & 127;
            *(float4*)&Wlds[k][c] = *(const float4*)&Wg[(kc * 64 + k) * DD + c];
        }
        __syncthreads();

#pragma unroll 8
        for (int k = 0; k < 64; ++k) {
            float a0 = Alds[ty * 4 + 0][k];
            float a1 = Alds[ty * 4 + 1][k];
            float a2 = Alds[ty * 4 + 2][k];
            float a3 = Alds[ty * 4 + 3][k];
            float4 w0 = *(float4*)&Wlds[k][tx * 8];
            float4 w1 = *(float4*)&Wlds[k][tx * 8 + 4];
            float w[8] = {w0.x, w0.y, w0.z, w0.w, w1.x, w1.y, w1.z, w1.w};
#pragma unroll
            for (int j = 0; j < 8; ++j) {
                acc[0][j] = fmaf(a0, w[j], acc[0][j]);
                acc[1][j] = fmaf(a1, w[j], acc[1][j]);
                acc[2][j] = fmaf(a2, w[j], acc[2][j]);
                acc[3][j] = fmaf(a3, w[j], acc[3][j]);
            }
        }
        __syncthreads();
    }

    float bcol[8];
    if (EPI == 1) {
#pragma unroll
        for (int j = 0; j < 8; ++j) bcol[j] = bias[tx * 8 + j];
    }
#pragma unroll
    for (int i = 0; i < 4; ++i) {
        int r = row0 + ty * 4 + i;
        if (r >= NN) break;
        float scale = (EPI == 0) ? dis[r] : 1.f;
        float o[8];
#pragma unroll
        for (int j = 0; j < 8; ++j) {
            float v = acc[i][j];
            if (EPI == 0) v *= scale;
            else          v = fmaxf(v + bcol[j], 0.f);
            o[j] = v;
        }
        *(float4*)&OUT[r * DD + tx * 8]     = make_float4(o[0], o[1], o[2], o[3]);
        *(float4*)&OUT[r * DD + tx * 8 + 4] = make_float4(o[4], o[5], o[6], o[7]);
    }
}

// ---------------- column-sliced gather + finalize + col stats ----------------
// slice = blockIdx & 7 (XCD round-robin): each XCD works one 16-col slice of HS
// (50000*16*4B = 3.2 MB -> L2-resident). Lane = (jj = lane>>4) neighbor sub-idx
// x (c = lane&15) column. 4 neighbors per round; shfl-reduce jj groups.
// Requires grid = 2048 blocks (256 blocks * 4 waves = 1024 waves per slice).
template<int RELU>
__global__ __launch_bounds__(256) void k_gather(const int* __restrict__ rowptr,
                                                const int* __restrict__ csr,
                                                const float* __restrict__ HS,
                                                const float* __restrict__ dis,
                                                const float* __restrict__ bias,
                                                float* __restrict__ OUT,
                                                float* __restrict__ colsum,
                                                float* __restrict__ colsumsq) {
    const int tid  = threadIdx.x;
    const int lane = tid & 63;
    const int wid  = tid >> 6;
    const int c    = lane & 15;            // column within slice
    const int jj   = lane >> 4;            // neighbor sub-index (0..3)
    const int slice = blockIdx.x & 7;
    const int cc   = slice * 16 + c;       // global column
    const int wgrp = (blockIdx.x >> 3) * 4 + wid;   // 0..1023 within slice
    const float b  = bias[cc];
    float sx = 0.f, sqx = 0.f;

    for (int r = wgrp; r < NN; r += 1024) {
        int beg = rowptr[r], end = rowptr[r + 1];
        float acc = (jj == 0) ? HS[(size_t)r * DD + cc] : 0.f;   // self loop
        int j = beg + jj;
        int s_cur = (j < end) ? csr[j] : 0;
        for (; j < end; j += 4) {
            int jn = j + 4;
            int s_next = (jn < end) ? csr[jn] : 0;   // prefetch next batch idx
            acc += HS[(size_t)s_cur * DD + cc];
            s_cur = s_next;
        }
        acc += __shfl_xor(acc, 16);
        acc += __shfl_xor(acc, 32);
        float v = fmaf(dis[r], acc, b);
        if (RELU) v = fmaxf(v, 0.f);
        if (jj == 0) {
            OUT[(size_t)r * DD + cc] = v;
            sx += v; sqx += v * v;
        }
    }

    // block stats reduction: valid lanes are jj==0 (16 per wave)
    __shared__ float2 red[4][16];
    if (jj == 0) red[wid][c] = make_float2(sx, sqx);
    __syncthreads();
    if (tid < 16) {
        float2 a0 = red[0][tid], a1 = red[1][tid], a2 = red[2][tid], a3 = red[3][tid];
        atomicAdd(&colsum[slice * 16 + tid],   (a0.x + a1.x) + (a2.x + a3.x));
        atomicAdd(&colsumsq[slice * 16 + tid], (a0.y + a1.y) + (a2.y + a3.y));
    }
}

// ---------------- head: out = sigmoid(H @ out_w + out_b) ----------------
__global__ __launch_bounds__(256) void k_head(const float* __restrict__ H,
                                              const float* __restrict__ ow,
                                              const float* __restrict__ ob,
                                              float* __restrict__ out) {
    int r = blockIdx.x * 4 + (threadIdx.x >> 6);
    if (r >= NN) return;
    int lane = threadIdx.x & 63;
    float2 h = ((const float2*)(H + (size_t)r * DD))[lane];
    float sum = h.x * ow[lane * 2] + h.y * ow[lane * 2 + 1];
#pragma unroll
    for (int off = 32; off > 0; off >>= 1) sum += __shfl_down(sum, off);
    if (lane == 0) {
        float z = sum + ob[0];
        out[r] = 1.f / (1.f + expf(-z));
    }
}

extern "C" void kernel_launch(void* const* d_in, const int* in_sizes, int n_in,
                              void* d_out, int out_size, void* d_ws, size_t ws_size,
                              hipStream_t stream) {
    const float* x      = (const float*)d_in[0];
    const int*   ei     = (const int*)d_in[1];
    const float* conv_w = (const float*)d_in[2];
    const float* conv_b = (const float*)d_in[3];
    const float* bn_g   = (const float*)d_in[4];
    const float* bn_b   = (const float*)d_in[5];
    const float* mlp_w  = (const float*)d_in[6];
    const float* mlp_b  = (const float*)d_in[7];
    const float* out_w  = (const float*)d_in[8];
    const float* out_b  = (const float*)d_in[9];
    float* out = (float*)d_out;

    const size_t ND4 = (size_t)NN * DD * 4;   // 25,600,000 B
    char* ws = (char*)d_ws;
    size_t off = 0;
    float* B0     = (float*)(ws + off); off += ND4;
    float* B1     = (float*)(ws + off); off += ND4;
    float* dis    = (float*)(ws + off); off += 204800;           // NN*4 rounded
    int*   deg    = (int*)  (ws + off); off += 204800;
    int*   rowptr = (int*)  (ws + off); off += 204804 + 60;      // NN+1, pad to align
    int*   cursor = (int*)  (ws + off); off += 204800;           // also scan scratch
    int*   bsum   = (int*)  (ws + off); off += 1024;
    int*   boff   = (int*)  (ws + off); off += 1024;
    float* cs     = (float*)(ws + off); off += 512;
    float* css    = (float*)(ws + off); off += 512;
    float* bnsc   = (float*)(ws + off); off += 512;
    float* bnsh   = (float*)(ws + off); off += 512;
    int*   csr    = (int*)  (ws + off); off += (size_t)EE * 4;
    // total ≈ 55.4 MB

    const int gemm_grid = (NN + 63) / 64;     // 782
    const int nscan = (NN + 255) / 256;       // 196
    const int gather_grid = 2048;             // must be 2048: 256 blocks/slice * 4 waves

    // ---- CSR build (graph static within launch) ----
    hipMemsetAsync(deg, 0, NN * sizeof(int), stream);
    k_deg<<<(EE + 255) / 256, 256, 0, stream>>>(ei, deg);
    k_dis<<<(NN + 255) / 256, 256, 0, stream>>>(deg, dis);
    k_scan_block<<<nscan, 256, 0, stream>>>(deg, cursor, bsum);
    k_scan_top<<<1, 256, 0, stream>>>(bsum, boff, rowptr + NN, nscan);
    k_scan_final<<<nscan, 256, 0, stream>>>(deg, cursor, boff, rowptr, cursor);
    k_fill<<<(EE + 255) / 256, 256, 0, stream>>>(ei, cursor, csr);

    // ---- layer 0: conv(x) ----
    k_gemm<0, 0><<<gemm_grid, 256, 0, stream>>>(x, conv_w, nullptr, dis, nullptr, nullptr, B1);
    hipMemsetAsync(cs, 0, 2 * DD * sizeof(float), stream);
    k_gather<0><<<gather_grid, 256, 0, stream>>>(rowptr, csr, B1, dis, conv_b, B0, cs, css);
    k_bnprep<<<1, 128, 0, stream>>>(cs, css, bn_g, bn_b, bnsc, bnsh);

    // ---- layer 1: conv(bn_relu(B0)) ----
    k_gemm<1, 0><<<gemm_grid, 256, 0, stream>>>(B0, conv_w + DD * DD, nullptr, dis, bnsc, bnsh, B1);
    hipMemsetAsync(cs, 0, 2 * DD * sizeof(float), stream);
    k_gather<0><<<gather_grid, 256, 0, stream>>>(rowptr, csr, B1, dis, conv_b + DD, B0, cs, css);
    k_bnprep<<<1, 128, 0, stream>>>(cs, css, bn_g + DD, bn_b + DD, bnsc, bnsh);

    // ---- layer 2: conv(bn_relu(B0)), relu'd gather, then BN (bns[-1]) ----
    k_gemm<1, 0><<<gemm_grid, 256, 0, stream>>>(B0, conv_w + 2 * DD * DD, nullptr, dis, bnsc, bnsh, B1);
    hipMemsetAsync(cs, 0, 2 * DD * sizeof(float), stream);
    k_gather<1><<<gather_grid, 256, 0, stream>>>(rowptr, csr, B1, dis, conv_b + 2 * DD, B0, cs, css);
    k_bnprep<<<1, 128, 0, stream>>>(cs, css, bn_g + DD, bn_b + DD, bnsc, bnsh);

    // ---- MLP head ----
    k_gemm<2, 1><<<gemm_grid, 256, 0, stream>>>(B0, mlp_w, mlp_b, dis, bnsc, bnsh, B1);
    k_gemm<0, 1><<<gemm_grid, 256, 0, stream>>>(B1, mlp_w + DD * DD, mlp_b + DD, dis, nullptr, nullptr, B0);
    k_head<<<(NN + 3) / 4, 256, 0, stream>>>(B0, out_w, out_b, out);
}

// Round 7
// 762.055 us; speedup vs baseline: 1.1332x; 1.1332x over previous
//
#include <hip/hip_runtime.h>
#include <hip/hip_bf16.h>

#define NN 50000
#define EE 800000
#define DD 128

__device__ __forceinline__ unsigned short f2bf(float f) {   // RNE
    unsigned int x = __float_as_uint(f);
    unsigned int r = x + 0x7fffu + ((x >> 16) & 1u);
    return (unsigned short)(r >> 16);
}
__device__ __forceinline__ float2 bf2x2(unsigned int u) {   // [lo,hi] bf16 pair
    return make_float2(__uint_as_float(u << 16), __uint_as_float(u & 0xffff0000u));
}

// ---------------- degree (guarded) ----------------
__global__ void k_deg(const int* __restrict__ ei, int* __restrict__ deg) {
    int e = blockIdx.x * 256 + threadIdx.x;
    if (e < EE) {
        int d = ei[EE + e];                       // dst row
        if (d >= 0 && d < NN) atomicAdd(&deg[d], 1);
    }
}

__global__ void k_dis(const int* __restrict__ deg, float* __restrict__ dis) {
    int i = blockIdx.x * 256 + threadIdx.x;
    if (i < NN) dis[i] = rsqrtf((float)deg[i] + 1.0f);  // +1 self loop; always >0
}

// ---------------- CSR build: block scan of deg -> rowptr ----------------
__global__ void k_scan_block(const int* __restrict__ deg, int* __restrict__ scanned,
                             int* __restrict__ blocksum) {
    __shared__ int lds[256];
    int t = threadIdx.x;
    int i = blockIdx.x * 256 + t;
    int v = (i < NN) ? deg[i] : 0;
    lds[t] = v;
    __syncthreads();
    for (int off = 1; off < 256; off <<= 1) {
        int add = (t >= off) ? lds[t - off] : 0;
        __syncthreads();
        lds[t] += add;
        __syncthreads();
    }
    if (i < NN) scanned[i] = lds[t];              // inclusive within block
    if (t == 255) blocksum[blockIdx.x] = lds[255];
}

__global__ void k_scan_top(const int* __restrict__ blocksum, int* __restrict__ blockoff,
                           int* __restrict__ rowptr_end, int nb) {
    __shared__ int lds[256];
    int t = threadIdx.x;
    int v = (t < nb) ? blocksum[t] : 0;
    lds[t] = v;
    __syncthreads();
    for (int off = 1; off < 256; off <<= 1) {
        int add = (t >= off) ? lds[t - off] : 0;
        __syncthreads();
        lds[t] += add;
        __syncthreads();
    }
    if (t < nb) blockoff[t] = lds[t] - v;         // exclusive
    if (t == nb - 1) *rowptr_end = lds[t];        // total valid edges -> rowptr[NN]
}

__global__ void k_scan_final(const int* __restrict__ deg, const int* __restrict__ scanned,
                             const int* __restrict__ blockoff,
                             int* __restrict__ rowptr, int* __restrict__ cursor) {
    int i = blockIdx.x * 256 + threadIdx.x;
    if (i < NN) {
        int v = scanned[i] - deg[i] + blockoff[blockIdx.x];  // global exclusive
        rowptr[i] = v;
        cursor[i] = v;
    }
}

__global__ void k_fill(const int* __restrict__ ei, int* __restrict__ cursor,
                       int* __restrict__ csr) {
    int e = blockIdx.x * 256 + threadIdx.x;
    if (e < EE) {
        int s = ei[e];
        int d = ei[EE + e];
        if ((unsigned)s < (unsigned)NN && (unsigned)d < (unsigned)NN) {
            int pos = atomicAdd(&cursor[d], 1);
            csr[pos] = s;
        }
    }
}

// ---------------- BN prep: scale/shift from col stats ----------------
__global__ void k_bnprep(const float* __restrict__ cs, const float* __restrict__ css,
                         const float* __restrict__ gamma, const float* __restrict__ beta,
                         float* __restrict__ bnsc, float* __restrict__ bnsh) {
    int d = threadIdx.x;
    const float invn = 1.f / (float)NN;
    float mean = cs[d] * invn;
    float var = css[d] * invn - mean * mean;
    float sc = gamma[d] * rsqrtf(fmaxf(var, 0.f) + 1e-5f);
    bnsc[d] = sc;
    bnsh[d] = beta[d] - mean * sc;
}

// ---------------- GEMM: OUT = pro(IN) @ W (+epilogue) ----------------
// PRO: 0=none, 1=BN+relu applied to A while staging, 2=BN only
// EPI: 0=scale rows by dis[r], write bf16 (conv pre-agg HS)
//      1=+bias then relu, write fp32 (mlp)
template<int PRO, int EPI>
__global__ __launch_bounds__(256) void k_gemm(const float* __restrict__ IN,
                                              const float* __restrict__ Wg,
                                              const float* __restrict__ bias,
                                              const float* __restrict__ dis,
                                              const float* __restrict__ bnsc,
                                              const float* __restrict__ bnsh,
                                              void* __restrict__ OUTv) {
    __shared__ float Alds[64][68];
    __shared__ float Wlds[64][128];
    const int tid = threadIdx.x;
    const int tx = tid & 15;
    const int ty = tid >> 4;
    const int row0 = blockIdx.x * 64;

    float acc[4][8];
#pragma unroll
    for (int i = 0; i < 4; ++i)
#pragma unroll
        for (int j = 0; j < 8; ++j) acc[i][j] = 0.f;

    for (int kc = 0; kc < 2; ++kc) {
#pragma unroll
        for (int it = 0; it < 4; ++it) {
            int idx = it * 1024 + tid * 4;
            int r = idx >> 6, k = idx & 63;
            int gr = row0 + r;
            float4 v = make_float4(0.f, 0.f, 0.f, 0.f);
            if (gr < NN) v = *(const float4*)&IN[gr * DD + kc * 64 + k];
            if (PRO) {
                float4 sc = *(const float4*)&bnsc[kc * 64 + k];
                float4 sh = *(const float4*)&bnsh[kc * 64 + k];
                v.x = fmaf(v.x, sc.x, sh.x);
                v.y = fmaf(v.y, sc.y, sh.y);
                v.z = fmaf(v.z, sc.z, sh.z);
                v.w = fmaf(v.w, sc.w, sh.w);
                if (PRO == 1) {
                    v.x = fmaxf(v.x, 0.f); v.y = fmaxf(v.y, 0.f);
                    v.z = fmaxf(v.z, 0.f); v.w = fmaxf(v.w, 0.f);
                }
            }
            *(float4*)&Alds[r][k] = v;
        }
#pragma unroll
        for (int it = 0; it < 8; ++it) {
            int idx = it * 1024 + tid * 4;
            int k = idx >> 7, c = idx & 127;
            *(float4*)&Wlds[k][c] = *(const float4*)&Wg[(kc * 64 + k) * DD + c];
        }
        __syncthreads();

#pragma unroll 8
        for (int k = 0; k < 64; ++k) {
            float a0 = Alds[ty * 4 + 0][k];
            float a1 = Alds[ty * 4 + 1][k];
            float a2 = Alds[ty * 4 + 2][k];
            float a3 = Alds[ty * 4 + 3][k];
            float4 w0 = *(float4*)&Wlds[k][tx * 8];
            float4 w1 = *(float4*)&Wlds[k][tx * 8 + 4];
            float w[8] = {w0.x, w0.y, w0.z, w0.w, w1.x, w1.y, w1.z, w1.w};
#pragma unroll
            for (int j = 0; j < 8; ++j) {
                acc[0][j] = fmaf(a0, w[j], acc[0][j]);
                acc[1][j] = fmaf(a1, w[j], acc[1][j]);
                acc[2][j] = fmaf(a2, w[j], acc[2][j]);
                acc[3][j] = fmaf(a3, w[j], acc[3][j]);
            }
        }
        __syncthreads();
    }

    float bcol[8];
    if (EPI == 1) {
#pragma unroll
        for (int j = 0; j < 8; ++j) bcol[j] = bias[tx * 8 + j];
    }
#pragma unroll
    for (int i = 0; i < 4; ++i) {
        int r = row0 + ty * 4 + i;
        if (r >= NN) break;
        if (EPI == 0) {
            float scale = dis[r];
            unsigned int p[4];
#pragma unroll
            for (int j = 0; j < 4; ++j) {
                unsigned short lo = f2bf(acc[i][2 * j] * scale);
                unsigned short hi = f2bf(acc[i][2 * j + 1] * scale);
                p[j] = (unsigned int)lo | ((unsigned int)hi << 16);
            }
            unsigned short* OB = (unsigned short*)OUTv;
            *(uint4*)&OB[(size_t)r * DD + tx * 8] = make_uint4(p[0], p[1], p[2], p[3]);
        } else {
            float o[8];
#pragma unroll
            for (int j = 0; j < 8; ++j) o[j] = fmaxf(acc[i][j] + bcol[j], 0.f);
            float* OF = (float*)OUTv;
            *(float4*)&OF[(size_t)r * DD + tx * 8]     = make_float4(o[0], o[1], o[2], o[3]);
            *(float4*)&OF[(size_t)r * DD + tx * 8 + 4] = make_float4(o[4], o[5], o[6], o[7]);
        }
    }
}

// ---------------- fused gather (bf16 HS) + finalize + col stats ----------------
// OUT[r] = relu?( dis[r] * (HS[r] + sum_{s in N(r)} HS[s]) + bias ), fp32 accum
template<int RELU>
__global__ __launch_bounds__(256) void k_gather(const int* __restrict__ rowptr,
                                                const int* __restrict__ csr,
                                                const unsigned int* __restrict__ HS2,  // bf16x2 rows
                                                const float* __restrict__ dis,
                                                const float* __restrict__ bias,
                                                float* __restrict__ OUT,
                                                float* __restrict__ colsum,
                                                float* __restrict__ colsumsq) {
    const int lane = threadIdx.x & 63;
    const int wid = threadIdx.x >> 6;
    float2 b = ((const float2*)bias)[lane];
    float sx = 0.f, sqx = 0.f, sy = 0.f, sqy = 0.f;

    const int ngroups = (NN + 3) / 4;
    for (int rg = blockIdx.x; rg < ngroups; rg += gridDim.x) {
        int r = rg * 4 + wid;
        if (r < NN) {
            int beg = rowptr[r], end = rowptr[r + 1];
            float2 acc = bf2x2(HS2[(size_t)r * 64 + lane]);   // self loop
            int j = beg;
            for (; j + 3 < end; j += 4) {
                int s0 = csr[j], s1 = csr[j + 1], s2 = csr[j + 2], s3 = csr[j + 3];
                unsigned int u0 = HS2[(size_t)s0 * 64 + lane];
                unsigned int u1 = HS2[(size_t)s1 * 64 + lane];
                unsigned int u2 = HS2[(size_t)s2 * 64 + lane];
                unsigned int u3 = HS2[(size_t)s3 * 64 + lane];
                float2 v0 = bf2x2(u0), v1 = bf2x2(u1), v2 = bf2x2(u2), v3 = bf2x2(u3);
                acc.x += (v0.x + v1.x) + (v2.x + v3.x);
                acc.y += (v0.y + v1.y) + (v2.y + v3.y);
            }
            for (; j < end; ++j) {
                int s = csr[j];
                float2 v = bf2x2(HS2[(size_t)s * 64 + lane]);
                acc.x += v.x;
                acc.y += v.y;
            }
            float dr = dis[r];
            float vx = fmaf(dr, acc.x, b.x);
            float vy = fmaf(dr, acc.y, b.y);
            if (RELU) { vx = fmaxf(vx, 0.f); vy = fmaxf(vy, 0.f); }
            ((float2*)(OUT + (size_t)r * DD))[lane] = make_float2(vx, vy);
            sx += vx; sqx += vx * vx;
            sy += vy; sqy += vy * vy;
        }
    }

    // block-level stats reduction: 4 waves -> wave 0 -> 256 atomics/block
    __shared__ float4 red[4][64];
    red[wid][lane] = make_float4(sx, sy, sqx, sqy);
    __syncthreads();
    if (wid == 0) {
        float4 a = red[0][lane], c = red[1][lane], d = red[2][lane], e = red[3][lane];
        atomicAdd(&colsum[2 * lane],       (a.x + c.x) + (d.x + e.x));
        atomicAdd(&colsum[2 * lane + 1],   (a.y + c.y) + (d.y + e.y));
        atomicAdd(&colsumsq[2 * lane],     (a.z + c.z) + (d.z + e.z));
        atomicAdd(&colsumsq[2 * lane + 1], (a.w + c.w) + (d.w + e.w));
    }
}

// ---------------- head: out = sigmoid(H @ out_w + out_b) ----------------
__global__ __launch_bounds__(256) void k_head(const float* __restrict__ H,
                                              const float* __restrict__ ow,
                                              const float* __restrict__ ob,
                                              float* __restrict__ out) {
    int r = blockIdx.x * 4 + (threadIdx.x >> 6);
    if (r >= NN) return;
    int lane = threadIdx.x & 63;
    float2 h = ((const float2*)(H + (size_t)r * DD))[lane];
    float sum = h.x * ow[lane * 2] + h.y * ow[lane * 2 + 1];
#pragma unroll
    for (int off = 32; off > 0; off >>= 1) sum += __shfl_down(sum, off);
    if (lane == 0) {
        float z = sum + ob[0];
        out[r] = 1.f / (1.f + expf(-z));
    }
}

extern "C" void kernel_launch(void* const* d_in, const int* in_sizes, int n_in,
                              void* d_out, int out_size, void* d_ws, size_t ws_size,
                              hipStream_t stream) {
    const float* x      = (const float*)d_in[0];
    const int*   ei     = (const int*)d_in[1];
    const float* conv_w = (const float*)d_in[2];
    const float* conv_b = (const float*)d_in[3];
    const float* bn_g   = (const float*)d_in[4];
    const float* bn_b   = (const float*)d_in[5];
    const float* mlp_w  = (const float*)d_in[6];
    const float* mlp_b  = (const float*)d_in[7];
    const float* out_w  = (const float*)d_in[8];
    const float* out_b  = (const float*)d_in[9];
    float* out = (float*)d_out;

    const size_t ND4 = (size_t)NN * DD * 4;   // 25,600,000 B
    char* ws = (char*)d_ws;
    size_t off = 0;
    float* B0      = (float*)(ws + off); off += ND4;            // fp32 features
    unsigned int* B1b = (unsigned int*)(ws + off); off += ND4 / 2;  // bf16 HS (12.8MB)
    float* B1f     = (float*)(ws + off); off += ND4;            // fp32 mlp hidden
    float* dis     = (float*)(ws + off); off += 204800;
    int*   deg     = (int*)  (ws + off); off += 204800;
    int*   rowptr  = (int*)  (ws + off); off += 204804 + 60;    // NN+1, pad
    int*   cursor  = (int*)  (ws + off); off += 204800;
    int*   bsum    = (int*)  (ws + off); off += 1024;
    int*   boff    = (int*)  (ws + off); off += 1024;
    float* cs      = (float*)(ws + off); off += 512;
    float* css     = (float*)(ws + off); off += 512;
    float* bnsc    = (float*)(ws + off); off += 512;
    float* bnsh    = (float*)(ws + off); off += 512;
    int*   csr     = (int*)  (ws + off); off += (size_t)EE * 4;
    // total ≈ 68.2 MB

    const int gemm_grid = (NN + 63) / 64;     // 782
    const int nscan = (NN + 255) / 256;       // 196
    const int gather_grid = 2048;             // 8192 waves

    // ---- CSR build (graph static within launch) ----
    hipMemsetAsync(deg, 0, NN * sizeof(int), stream);
    k_deg<<<(EE + 255) / 256, 256, 0, stream>>>(ei, deg);
    k_dis<<<(NN + 255) / 256, 256, 0, stream>>>(deg, dis);
    k_scan_block<<<nscan, 256, 0, stream>>>(deg, cursor, bsum);
    k_scan_top<<<1, 256, 0, stream>>>(bsum, boff, rowptr + NN, nscan);
    k_scan_final<<<nscan, 256, 0, stream>>>(deg, cursor, boff, rowptr, cursor);
    k_fill<<<(EE + 255) / 256, 256, 0, stream>>>(ei, cursor, csr);

    // ---- layer 0: conv(x) ----
    k_gemm<0, 0><<<gemm_grid, 256, 0, stream>>>(x, conv_w, nullptr, dis, nullptr, nullptr, B1b);
    hipMemsetAsync(cs, 0, 2 * DD * sizeof(float), stream);
    k_gather<0><<<gather_grid, 256, 0, stream>>>(rowptr, csr, B1b, dis, conv_b, B0, cs, css);
    k_bnprep<<<1, 128, 0, stream>>>(cs, css, bn_g, bn_b, bnsc, bnsh);

    // ---- layer 1: conv(bn_relu(B0)) ----
    k_gemm<1, 0><<<gemm_grid, 256, 0, stream>>>(B0, conv_w + DD * DD, nullptr, dis, bnsc, bnsh, B1b);
    hipMemsetAsync(cs, 0, 2 * DD * sizeof(float), stream);
    k_gather<0><<<gather_grid, 256, 0, stream>>>(rowptr, csr, B1b, dis, conv_b + DD, B0, cs, css);
    k_bnprep<<<1, 128, 0, stream>>>(cs, css, bn_g + DD, bn_b + DD, bnsc, bnsh);

    // ---- layer 2: conv(bn_relu(B0)), relu'd gather, then BN (bns[-1]) ----
    k_gemm<1, 0><<<gemm_grid, 256, 0, stream>>>(B0, conv_w + 2 * DD * DD, nullptr, dis, bnsc, bnsh, B1b);
    hipMemsetAsync(cs, 0, 2 * DD * sizeof(float), stream);
    k_gather<1><<<gather_grid, 256, 0, stream>>>(rowptr, csr, B1b, dis, conv_b + 2 * DD, B0, cs, css);
    k_bnprep<<<1, 128, 0, stream>>>(cs, css, bn_g + DD, bn_b + DD, bnsc, bnsh);

    // ---- MLP head ----
    k_gemm<2, 1><<<gemm_grid, 256, 0, stream>>>(B0, mlp_w, mlp_b, dis, bnsc, bnsh, B1f);
    k_gemm<0, 1><<<gemm_grid, 256, 0, stream>>>(B1f, mlp_w + DD * DD, mlp_b + DD, dis, nullptr, nullptr, B0);
    k_head<<<(NN + 3) / 4, 256, 0, stream>>>(B0, out_w, out_b, out);
}

// Round 8
// 625.140 us; speedup vs baseline: 1.3814x; 1.2190x over previous
//
#include <hip/hip_runtime.h>
#include <hip/hip_bf16.h>

#define NN 50000
#define EE 800000
#define DD 128

__device__ __forceinline__ unsigned short f2bf(float f) {   // RNE
    unsigned int x = __float_as_uint(f);
    unsigned int r = x + 0x7fffu + ((x >> 16) & 1u);
    return (unsigned short)(r >> 16);
}
__device__ __forceinline__ float2 bf2x2(unsigned int u) {   // [lo,hi] bf16 pair
    return make_float2(__uint_as_float(u << 16), __uint_as_float(u & 0xffff0000u));
}

// ---------------- degree (guarded) ----------------
__global__ void k_deg(const int* __restrict__ ei, int* __restrict__ deg) {
    int e = blockIdx.x * 256 + threadIdx.x;
    if (e < EE) {
        int d = ei[EE + e];                       // dst row
        if (d >= 0 && d < NN) atomicAdd(&deg[d], 1);
    }
}

__global__ void k_dis(const int* __restrict__ deg, float* __restrict__ dis) {
    int i = blockIdx.x * 256 + threadIdx.x;
    if (i < NN) dis[i] = rsqrtf((float)deg[i] + 1.0f);  // +1 self loop; always >0
}

// ---------------- CSR build: block scan of deg -> rowptr ----------------
__global__ void k_scan_block(const int* __restrict__ deg, int* __restrict__ scanned,
                             int* __restrict__ blocksum) {
    __shared__ int lds[256];
    int t = threadIdx.x;
    int i = blockIdx.x * 256 + t;
    int v = (i < NN) ? deg[i] : 0;
    lds[t] = v;
    __syncthreads();
    for (int off = 1; off < 256; off <<= 1) {
        int add = (t >= off) ? lds[t - off] : 0;
        __syncthreads();
        lds[t] += add;
        __syncthreads();
    }
    if (i < NN) scanned[i] = lds[t];              // inclusive within block
    if (t == 255) blocksum[blockIdx.x] = lds[255];
}

__global__ void k_scan_top(const int* __restrict__ blocksum, int* __restrict__ blockoff,
                           int* __restrict__ rowptr_end, int nb) {
    __shared__ int lds[256];
    int t = threadIdx.x;
    int v = (t < nb) ? blocksum[t] : 0;
    lds[t] = v;
    __syncthreads();
    for (int off = 1; off < 256; off <<= 1) {
        int add = (t >= off) ? lds[t - off] : 0;
        __syncthreads();
        lds[t] += add;
        __syncthreads();
    }
    if (t < nb) blockoff[t] = lds[t] - v;         // exclusive
    if (t == nb - 1) *rowptr_end = lds[t];        // total valid edges -> rowptr[NN]
}

__global__ void k_scan_final(const int* __restrict__ deg, const int* __restrict__ scanned,
                             const int* __restrict__ blockoff,
                             int* __restrict__ rowptr, int* __restrict__ cursor) {
    int i = blockIdx.x * 256 + threadIdx.x;
    if (i < NN) {
        int v = scanned[i] - deg[i] + blockoff[blockIdx.x];  // global exclusive
        rowptr[i] = v;
        cursor[i] = v;
    }
}

__global__ void k_fill(const int* __restrict__ ei, int* __restrict__ cursor,
                       int* __restrict__ csr) {
    int e = blockIdx.x * 256 + threadIdx.x;
    if (e < EE) {
        int s = ei[e];
        int d = ei[EE + e];
        if ((unsigned)s < (unsigned)NN && (unsigned)d < (unsigned)NN) {
            int pos = atomicAdd(&cursor[d], 1);
            csr[pos] = s;
        }
    }
}

// ---------------- BN prep: scale/shift from col stats ----------------
__global__ void k_bnprep(const float* __restrict__ cs, const float* __restrict__ css,
                         const float* __restrict__ gamma, const float* __restrict__ beta,
                         float* __restrict__ bnsc, float* __restrict__ bnsh) {
    int d = threadIdx.x;
    const float invn = 1.f / (float)NN;
    float mean = cs[d] * invn;
    float var = css[d] * invn - mean * mean;
    float sc = gamma[d] * rsqrtf(fmaxf(var, 0.f) + 1e-5f);
    bnsc[d] = sc;
    bnsh[d] = beta[d] - mean * sc;
}

// ---------------- GEMM: OUT = pro(IN) @ W (+epilogue) ----------------
// PRO: 0=none, 1=BN+relu applied to A while staging, 2=BN only
// EPI: 0=scale rows by dis[r], write bf16 (conv pre-agg HS)
//      1=+bias then relu, write fp32 (mlp)
template<int PRO, int EPI>
__global__ __launch_bounds__(256) void k_gemm(const float* __restrict__ IN,
                                              const float* __restrict__ Wg,
                                              const float* __restrict__ bias,
                                              const float* __restrict__ dis,
                                              const float* __restrict__ bnsc,
                                              const float* __restrict__ bnsh,
                                              void* __restrict__ OUTv) {
    __shared__ float Alds[64][68];
    __shared__ float Wlds[64][128];
    const int tid = threadIdx.x;
    const int tx = tid & 15;
    const int ty = tid >> 4;
    const int row0 = blockIdx.x * 64;

    float acc[4][8];
#pragma unroll
    for (int i = 0; i < 4; ++i)
#pragma unroll
        for (int j = 0; j < 8; ++j) acc[i][j] = 0.f;

    for (int kc = 0; kc < 2; ++kc) {
#pragma unroll
        for (int it = 0; it < 4; ++it) {
            int idx = it * 1024 + tid * 4;
            int r = idx >> 6, k = idx & 63;
            int gr = row0 + r;
            float4 v = make_float4(0.f, 0.f, 0.f, 0.f);
            if (gr < NN) v = *(const float4*)&IN[gr * DD + kc * 64 + k];
            if (PRO) {
                float4 sc = *(const float4*)&bnsc[kc * 64 + k];
                float4 sh = *(const float4*)&bnsh[kc * 64 + k];
                v.x = fmaf(v.x, sc.x, sh.x);
                v.y = fmaf(v.y, sc.y, sh.y);
                v.z = fmaf(v.z, sc.z, sh.z);
                v.w = fmaf(v.w, sc.w, sh.w);
                if (PRO == 1) {
                    v.x = fmaxf(v.x, 0.f); v.y = fmaxf(v.y, 0.f);
                    v.z = fmaxf(v.z, 0.f); v.w = fmaxf(v.w, 0.f);
                }
            }
            *(float4*)&Alds[r][k] = v;
        }
#pragma unroll
        for (int it = 0; it < 8; ++it) {
            int idx = it * 1024 + tid * 4;
            int k = idx >> 7, c = idx & 127;
            *(float4*)&Wlds[k][c] = *(const float4*)&Wg[(kc * 64 + k) * DD + c];
        }
        __syncthreads();

#pragma unroll 8
        for (int k = 0; k < 64; ++k) {
            float a0 = Alds[ty * 4 + 0][k];
            float a1 = Alds[ty * 4 + 1][k];
            float a2 = Alds[ty * 4 + 2][k];
            float a3 = Alds[ty * 4 + 3][k];
            float4 w0 = *(float4*)&Wlds[k][tx * 8];
            float4 w1 = *(float4*)&Wlds[k][tx * 8 + 4];
            float w[8] = {w0.x, w0.y, w0.z, w0.w, w1.x, w1.y, w1.z, w1.w};
#pragma unroll
            for (int j = 0; j < 8; ++j) {
                acc[0][j] = fmaf(a0, w[j], acc[0][j]);
                acc[1][j] = fmaf(a1, w[j], acc[1][j]);
                acc[2][j] = fmaf(a2, w[j], acc[2][j]);
                acc[3][j] = fmaf(a3, w[j], acc[3][j]);
            }
        }
        __syncthreads();
    }

    float bcol[8];
    if (EPI == 1) {
#pragma unroll
        for (int j = 0; j < 8; ++j) bcol[j] = bias[tx * 8 + j];
    }
#pragma unroll
    for (int i = 0; i < 4; ++i) {
        int r = row0 + ty * 4 + i;
        if (r >= NN) break;
        if (EPI == 0) {
            float scale = dis[r];
            unsigned int p[4];
#pragma unroll
            for (int j = 0; j < 4; ++j) {
                unsigned short lo = f2bf(acc[i][2 * j] * scale);
                unsigned short hi = f2bf(acc[i][2 * j + 1] * scale);
                p[j] = (unsigned int)lo | ((unsigned int)hi << 16);
            }
            unsigned short* OB = (unsigned short*)OUTv;
            *(uint4*)&OB[(size_t)r * DD + tx * 8] = make_uint4(p[0], p[1], p[2], p[3]);
        } else {
            float o[8];
#pragma unroll
            for (int j = 0; j < 8; ++j) o[j] = fmaxf(acc[i][j] + bcol[j], 0.f);
            float* OF = (float*)OUTv;
            *(float4*)&OF[(size_t)r * DD + tx * 8]     = make_float4(o[0], o[1], o[2], o[3]);
            *(float4*)&OF[(size_t)r * DD + tx * 8 + 4] = make_float4(o[4], o[5], o[6], o[7]);
        }
    }
}

// ---------------- fused gather (bf16 HS, 16-neighbor MLP) ----------------
// Wave layout: jj=lane>>4 selects neighbor slot (0..3), c=lane&15 selects the
// 16B chunk (8 bf16 cols) of the row. One uint4 load serves 4 neighbor rows
// per instruction; 4-wide unroll => 16 neighbors in flight per round.
// Cross-jj combine via shfl_xor; jj==0 lanes finalize, write, keep col stats.
template<int RELU>
__global__ __launch_bounds__(256) void k_gather(const int* __restrict__ rowptr,
                                                const int* __restrict__ csr,
                                                const uint4* __restrict__ HSq,  // bf16 rows, 16B granules
                                                const float* __restrict__ dis,
                                                const float* __restrict__ bias,
                                                float* __restrict__ OUT,
                                                float* __restrict__ colsum,
                                                float* __restrict__ colsumsq) {
    const int tid = threadIdx.x;
    const int lane = tid & 63;
    const int wid = tid >> 6;
    const int c = lane & 15;            // 16B chunk -> cols 8c..8c+7
    const int jj = lane >> 4;           // neighbor slot
    const int gwave = blockIdx.x * 4 + wid;     // 0..8191

    float4 bia0 = ((const float4*)bias)[2 * c];
    float4 bia1 = ((const float4*)bias)[2 * c + 1];
    float sum[8], sq[8];
#pragma unroll
    for (int t = 0; t < 8; ++t) { sum[t] = 0.f; sq[t] = 0.f; }

    for (int r = gwave; r < NN; r += 8192) {
        int beg = rowptr[r], end = rowptr[r + 1];
        float a[8];
#pragma unroll
        for (int t = 0; t < 8; ++t) a[t] = 0.f;

        // self loop (jj==0 lanes only; counted once after shfl reduce)
        if (jj == 0) {
            uint4 u = HSq[(size_t)r * 16 + c];
            float2 p0 = bf2x2(u.x), p1 = bf2x2(u.y), p2 = bf2x2(u.z), p3 = bf2x2(u.w);
            a[0] += p0.x; a[1] += p0.y; a[2] += p1.x; a[3] += p1.y;
            a[4] += p2.x; a[5] += p2.y; a[6] += p3.x; a[7] += p3.y;
        }

        int e1 = end - 1;
        for (int j = beg; j < end; j += 16) {
            int i0 = j + jj, i1 = j + 4 + jj, i2 = j + 8 + jj, i3 = j + 12 + jj;
            int s0 = csr[min(i0, e1)];
            int s1 = csr[min(i1, e1)];
            int s2 = csr[min(i2, e1)];
            int s3 = csr[min(i3, e1)];
            uint4 v0 = HSq[(size_t)s0 * 16 + c];
            uint4 v1 = HSq[(size_t)s1 * 16 + c];
            uint4 v2 = HSq[(size_t)s2 * 16 + c];
            uint4 v3 = HSq[(size_t)s3 * 16 + c];
            if (i0 < end) {
                float2 p0 = bf2x2(v0.x), p1 = bf2x2(v0.y), p2 = bf2x2(v0.z), p3 = bf2x2(v0.w);
                a[0] += p0.x; a[1] += p0.y; a[2] += p1.x; a[3] += p1.y;
                a[4] += p2.x; a[5] += p2.y; a[6] += p3.x; a[7] += p3.y;
            }
            if (i1 < end) {
                float2 p0 = bf2x2(v1.x), p1 = bf2x2(v1.y), p2 = bf2x2(v1.z), p3 = bf2x2(v1.w);
                a[0] += p0.x; a[1] += p0.y; a[2] += p1.x; a[3] += p1.y;
                a[4] += p2.x; a[5] += p2.y; a[6] += p3.x; a[7] += p3.y;
            }
            if (i2 < end) {
                float2 p0 = bf2x2(v2.x), p1 = bf2x2(v2.y), p2 = bf2x2(v2.z), p3 = bf2x2(v2.w);
                a[0] += p0.x; a[1] += p0.y; a[2] += p1.x; a[3] += p1.y;
                a[4] += p2.x; a[5] += p2.y; a[6] += p3.x; a[7] += p3.y;
            }
            if (i3 < end) {
                float2 p0 = bf2x2(v3.x), p1 = bf2x2(v3.y), p2 = bf2x2(v3.z), p3 = bf2x2(v3.w);
                a[0] += p0.x; a[1] += p0.y; a[2] += p1.x; a[3] += p1.y;
                a[4] += p2.x; a[5] += p2.y; a[6] += p3.x; a[7] += p3.y;
            }
        }

#pragma unroll
        for (int t = 0; t < 8; ++t) {
            a[t] += __shfl_xor(a[t], 16);
            a[t] += __shfl_xor(a[t], 32);
        }

        if (jj == 0) {
            float dr = dis[r];
            float v[8];
            v[0] = fmaf(dr, a[0], bia0.x); v[1] = fmaf(dr, a[1], bia0.y);
            v[2] = fmaf(dr, a[2], bia0.z); v[3] = fmaf(dr, a[3], bia0.w);
            v[4] = fmaf(dr, a[4], bia1.x); v[5] = fmaf(dr, a[5], bia1.y);
            v[6] = fmaf(dr, a[6], bia1.z); v[7] = fmaf(dr, a[7], bia1.w);
            if (RELU) {
#pragma unroll
                for (int t = 0; t < 8; ++t) v[t] = fmaxf(v[t], 0.f);
            }
            float* op = OUT + (size_t)r * DD + c * 8;
            *(float4*)op       = make_float4(v[0], v[1], v[2], v[3]);
            *(float4*)(op + 4) = make_float4(v[4], v[5], v[6], v[7]);
#pragma unroll
            for (int t = 0; t < 8; ++t) { sum[t] += v[t]; sq[t] += v[t] * v[t]; }
        }
    }

    // stats: jj==0 lanes hold 8 cols each -> LDS -> 128 threads -> 256 atomics
    __shared__ float redS[4][16][8];
    __shared__ float redQ[4][16][8];
    if (jj == 0) {
#pragma unroll
        for (int t = 0; t < 8; ++t) { redS[wid][c][t] = sum[t]; redQ[wid][c][t] = sq[t]; }
    }
    __syncthreads();
    if (tid < 128) {
        int ci = tid >> 3, ct = tid & 7;
        float S = (redS[0][ci][ct] + redS[1][ci][ct]) + (redS[2][ci][ct] + redS[3][ci][ct]);
        float Q = (redQ[0][ci][ct] + redQ[1][ci][ct]) + (redQ[2][ci][ct] + redQ[3][ci][ct]);
        atomicAdd(&colsum[tid], S);
        atomicAdd(&colsumsq[tid], Q);
    }
}

// ---------------- head: out = sigmoid(H @ out_w + out_b) ----------------
__global__ __launch_bounds__(256) void k_head(const float* __restrict__ H,
                                              const float* __restrict__ ow,
                                              const float* __restrict__ ob,
                                              float* __restrict__ out) {
    int r = blockIdx.x * 4 + (threadIdx.x >> 6);
    if (r >= NN) return;
    int lane = threadIdx.x & 63;
    float2 h = ((const float2*)(H + (size_t)r * DD))[lane];
    float sum = h.x * ow[lane * 2] + h.y * ow[lane * 2 + 1];
#pragma unroll
    for (int off = 32; off > 0; off >>= 1) sum += __shfl_down(sum, off);
    if (lane == 0) {
        float z = sum + ob[0];
        out[r] = 1.f / (1.f + expf(-z));
    }
}

extern "C" void kernel_launch(void* const* d_in, const int* in_sizes, int n_in,
                              void* d_out, int out_size, void* d_ws, size_t ws_size,
                              hipStream_t stream) {
    const float* x      = (const float*)d_in[0];
    const int*   ei     = (const int*)d_in[1];
    const float* conv_w = (const float*)d_in[2];
    const float* conv_b = (const float*)d_in[3];
    const float* bn_g   = (const float*)d_in[4];
    const float* bn_b   = (const float*)d_in[5];
    const float* mlp_w  = (const float*)d_in[6];
    const float* mlp_b  = (const float*)d_in[7];
    const float* out_w  = (const float*)d_in[8];
    const float* out_b  = (const float*)d_in[9];
    float* out = (float*)d_out;

    const size_t ND4 = (size_t)NN * DD * 4;   // 25,600,000 B
    char* ws = (char*)d_ws;
    size_t off = 0;
    float* B0      = (float*)(ws + off); off += ND4;            // fp32 features
    uint4* B1b     = (uint4*)(ws + off); off += ND4 / 2;        // bf16 HS (12.8MB)
    float* B1f     = (float*)(ws + off); off += ND4;            // fp32 mlp hidden
    float* dis     = (float*)(ws + off); off += 204800;
    int*   deg     = (int*)  (ws + off); off += 204800;
    int*   rowptr  = (int*)  (ws + off); off += 204804 + 60;    // NN+1, pad
    int*   cursor  = (int*)  (ws + off); off += 204800;
    int*   bsum    = (int*)  (ws + off); off += 1024;
    int*   boff    = (int*)  (ws + off); off += 1024;
    float* cs      = (float*)(ws + off); off += 512;
    float* css     = (float*)(ws + off); off += 512;
    float* bnsc    = (float*)(ws + off); off += 512;
    float* bnsh    = (float*)(ws + off); off += 512;
    int*   csr     = (int*)  (ws + off); off += (size_t)EE * 4;
    // total ≈ 68.2 MB

    const int gemm_grid = (NN + 63) / 64;     // 782
    const int nscan = (NN + 255) / 256;       // 196
    const int gather_grid = 2048;             // 8192 waves

    // ---- CSR build (graph static within launch) ----
    hipMemsetAsync(deg, 0, NN * sizeof(int), stream);
    k_deg<<<(EE + 255) / 256, 256, 0, stream>>>(ei, deg);
    k_dis<<<(NN + 255) / 256, 256, 0, stream>>>(deg, dis);
    k_scan_block<<<nscan, 256, 0, stream>>>(deg, cursor, bsum);
    k_scan_top<<<1, 256, 0, stream>>>(bsum, boff, rowptr + NN, nscan);
    k_scan_final<<<nscan, 256, 0, stream>>>(deg, cursor, boff, rowptr, cursor);
    k_fill<<<(EE + 255) / 256, 256, 0, stream>>>(ei, cursor, csr);

    // ---- layer 0: conv(x) ----
    k_gemm<0, 0><<<gemm_grid, 256, 0, stream>>>(x, conv_w, nullptr, dis, nullptr, nullptr, B1b);
    hipMemsetAsync(cs, 0, 2 * DD * sizeof(float), stream);
    k_gather<0><<<gather_grid, 256, 0, stream>>>(rowptr, csr, B1b, dis, conv_b, B0, cs, css);
    k_bnprep<<<1, 128, 0, stream>>>(cs, css, bn_g, bn_b, bnsc, bnsh);

    // ---- layer 1: conv(bn_relu(B0)) ----
    k_gemm<1, 0><<<gemm_grid, 256, 0, stream>>>(B0, conv_w + DD * DD, nullptr, dis, bnsc, bnsh, B1b);
    hipMemsetAsync(cs, 0, 2 * DD * sizeof(float), stream);
    k_gather<0><<<gather_grid, 256, 0, stream>>>(rowptr, csr, B1b, dis, conv_b + DD, B0, cs, css);
    k_bnprep<<<1, 128, 0, stream>>>(cs, css, bn_g + DD, bn_b + DD, bnsc, bnsh);

    // ---- layer 2: conv(bn_relu(B0)), relu'd gather, then BN (bns[-1]) ----
    k_gemm<1, 0><<<gemm_grid, 256, 0, stream>>>(B0, conv_w + 2 * DD * DD, nullptr, dis, bnsc, bnsh, B1b);
    hipMemsetAsync(cs, 0, 2 * DD * sizeof(float), stream);
    k_gather<1><<<gather_grid, 256, 0, stream>>>(rowptr, csr, B1b, dis, conv_b + 2 * DD, B0, cs, css);
    k_bnprep<<<1, 128, 0, stream>>>(cs, css, bn_g + DD, bn_b + DD, bnsc, bnsh);

    // ---- MLP head ----
    k_gemm<2, 1><<<gemm_grid, 256, 0, stream>>>(B0, mlp_w, mlp_b, dis, bnsc, bnsh, B1f);
    k_gemm<0, 1><<<gemm_grid, 256, 0, stream>>>(B1f, mlp_w + DD * DD, mlp_b + DD, dis, nullptr, nullptr, B0);
    k_head<<<(NN + 3) / 4, 256, 0, stream>>>(B0, out_w, out_b, out);
}

// Round 10
// 548.253 us; speedup vs baseline: 1.5751x; 1.1402x over previous
//
#include <hip/hip_runtime.h>
#include <hip/hip_bf16.h>

#define NN 50000
#define EE 800000
#define DD 128

typedef __attribute__((ext_vector_type(8))) short short8;
typedef __attribute__((ext_vector_type(4))) float floatx4;

__device__ __forceinline__ unsigned short f2bf(float f) {   // RNE
    unsigned int x = __float_as_uint(f);
    unsigned int r = x + 0x7fffu + ((x >> 16) & 1u);
    return (unsigned short)(r >> 16);
}
__device__ __forceinline__ float2 bf2x2(unsigned int u) {   // [lo,hi] bf16 pair
    return make_float2(__uint_as_float(u << 16), __uint_as_float(u & 0xffff0000u));
}

// ---------------- degree (guarded) ----------------
__global__ void k_deg(const int* __restrict__ ei, int* __restrict__ deg) {
    int e = blockIdx.x * 256 + threadIdx.x;
    if (e < EE) {
        int d = ei[EE + e];
        if (d >= 0 && d < NN) atomicAdd(&deg[d], 1);
    }
}

__global__ void k_dis(const int* __restrict__ deg, float* __restrict__ dis) {
    int i = blockIdx.x * 256 + threadIdx.x;
    if (i < NN) dis[i] = rsqrtf((float)deg[i] + 1.0f);
}

// ---------------- CSR build ----------------
__global__ void k_scan_block(const int* __restrict__ deg, int* __restrict__ scanned,
                             int* __restrict__ blocksum) {
    __shared__ int lds[256];
    int t = threadIdx.x;
    int i = blockIdx.x * 256 + t;
    int v = (i < NN) ? deg[i] : 0;
    lds[t] = v;
    __syncthreads();
    for (int off = 1; off < 256; off <<= 1) {
        int add = (t >= off) ? lds[t - off] : 0;
        __syncthreads();
        lds[t] += add;
        __syncthreads();
    }
    if (i < NN) scanned[i] = lds[t];
    if (t == 255) blocksum[blockIdx.x] = lds[255];
}

__global__ void k_scan_top(const int* __restrict__ blocksum, int* __restrict__ blockoff,
                           int* __restrict__ rowptr_end, int nb) {
    __shared__ int lds[256];
    int t = threadIdx.x;
    int v = (t < nb) ? blocksum[t] : 0;
    lds[t] = v;
    __syncthreads();
    for (int off = 1; off < 256; off <<= 1) {
        int add = (t >= off) ? lds[t - off] : 0;
        __syncthreads();
        lds[t] += add;
        __syncthreads();
    }
    if (t < nb) blockoff[t] = lds[t] - v;
    if (t == nb - 1) *rowptr_end = lds[t];
}

__global__ void k_scan_final(const int* __restrict__ deg, const int* __restrict__ scanned,
                             const int* __restrict__ blockoff,
                             int* __restrict__ rowptr, int* __restrict__ cursor) {
    int i = blockIdx.x * 256 + threadIdx.x;
    if (i < NN) {
        int v = scanned[i] - deg[i] + blockoff[blockIdx.x];
        rowptr[i] = v;
        cursor[i] = v;
    }
}

__global__ void k_fill(const int* __restrict__ ei, int* __restrict__ cursor,
                       int* __restrict__ csr) {
    int e = blockIdx.x * 256 + threadIdx.x;
    if (e < EE) {
        int s = ei[e];
        int d = ei[EE + e];
        if ((unsigned)s < (unsigned)NN && (unsigned)d < (unsigned)NN) {
            int pos = atomicAdd(&cursor[d], 1);
            csr[pos] = s;
        }
    }
}

// ---------------- BN prep ----------------
__global__ void k_bnprep(const float* __restrict__ cs, const float* __restrict__ css,
                         const float* __restrict__ gamma, const float* __restrict__ beta,
                         float* __restrict__ bnsc, float* __restrict__ bnsh) {
    int d = threadIdx.x;
    const float invn = 1.f / (float)NN;
    float mean = cs[d] * invn;
    float var = css[d] * invn - mean * mean;
    float sc = gamma[d] * rsqrtf(fmaxf(var, 0.f) + 1e-5f);
    bnsc[d] = sc;
    bnsh[d] = beta[d] - mean * sc;
}

// ---------------- W prep: fp32 [k][c] -> bf16 transposed [c][k], all 5 mats ----
__global__ void k_wprep(const float* __restrict__ conv_w, const float* __restrict__ mlp_w,
                        unsigned short* __restrict__ Wt) {
    int g = blockIdx.x * 256 + threadIdx.x;        // [0, 81920)
    int mat = g >> 14;
    int rem = g & 16383;
    int k = rem >> 7, c = rem & 127;               // read coalesced over c
    const float* src = (mat < 3) ? (conv_w + mat * 16384) : (mlp_w + (mat - 3) * 16384);
    Wt[mat * 16384 + c * 128 + k] = f2bf(src[k * 128 + c]);
}

// ---------------- MFMA GEMM: OUT = pro(IN) @ W (+epilogue) ----------------
// PRO: 0=none, 1=BN+relu on A while staging, 2=BN only
// EPI: 0=row-scale by dis -> bf16 out (conv HS), 1=+bias,relu -> fp32 out (mlp)
// Wt: bf16 [c][k] (pre-transposed). Block: 64 rows x 128 cols, 4 waves.
// LDS rows padded to 136 bf16 to break bank aliasing.
#define LSTR 136
template<int PRO, int EPI>
__global__ __launch_bounds__(256) void k_gemm_mfma(const float* __restrict__ IN,
                                                   const unsigned short* __restrict__ Wt,
                                                   const float* __restrict__ bias,
                                                   const float* __restrict__ dis,
                                                   const float* __restrict__ bnsc,
                                                   const float* __restrict__ bnsh,
                                                   void* __restrict__ OUTv) {
    __shared__ unsigned short Wl[128 * LSTR];   // [c][k] 34KB
    __shared__ unsigned short Al[64 * LSTR];    // [r][k] 17KB
    const int tid = threadIdx.x;
    const int lane = tid & 63;
    const int w = tid >> 6;
    const int row0 = blockIdx.x * 64;

    // stage Wt: 2048 granules of 16B; each 128-elem row = 16 granules
    {
        const uint4* src = (const uint4*)Wt;
#pragma unroll
        for (int i = 0; i < 8; ++i) {
            int g = tid + 256 * i;                // granule id
            int c = g >> 4, gi = g & 15;          // FIXED: 16 granules per row
            *(uint4*)&Wl[c * LSTR + gi * 8] = src[g];
        }
    }
    // stage A: thread -> row tid>>2, k-quarter (tid&3)*32, BN while staging
    {
        int r = tid >> 2, kq = (tid & 3) * 32;
        int gr = row0 + r;
        unsigned short tmp[32];
#pragma unroll
        for (int i = 0; i < 8; ++i) {
            float4 v = make_float4(0.f, 0.f, 0.f, 0.f);
            if (gr < NN) v = *(const float4*)&IN[(size_t)gr * DD + kq + i * 4];
            if (PRO) {
                float4 sc = *(const float4*)&bnsc[kq + i * 4];
                float4 sh = *(const float4*)&bnsh[kq + i * 4];
                v.x = fmaf(v.x, sc.x, sh.x);
                v.y = fmaf(v.y, sc.y, sh.y);
                v.z = fmaf(v.z, sc.z, sh.z);
                v.w = fmaf(v.w, sc.w, sh.w);
                if (PRO == 1) {
                    v.x = fmaxf(v.x, 0.f); v.y = fmaxf(v.y, 0.f);
                    v.z = fmaxf(v.z, 0.f); v.w = fmaxf(v.w, 0.f);
                }
            }
            tmp[i * 4 + 0] = f2bf(v.x); tmp[i * 4 + 1] = f2bf(v.y);
            tmp[i * 4 + 2] = f2bf(v.z); tmp[i * 4 + 3] = f2bf(v.w);
        }
#pragma unroll
        for (int j = 0; j < 4; ++j)
            *(uint4*)&Al[r * LSTR + kq + j * 8] = ((uint4*)tmp)[j];
    }
    __syncthreads();

    const int n = lane & 15, q = lane >> 4;
    floatx4 acc[4][2];
#pragma unroll
    for (int mt = 0; mt < 4; ++mt)
#pragma unroll
        for (int nt = 0; nt < 2; ++nt)
            acc[mt][nt] = (floatx4){0.f, 0.f, 0.f, 0.f};

#pragma unroll
    for (int kk = 0; kk < 4; ++kk) {
        int ko = kk * 32 + q * 8;
        short8 b0 = *(const short8*)&Wl[(w * 32 + n) * LSTR + ko];
        short8 b1 = *(const short8*)&Wl[(w * 32 + 16 + n) * LSTR + ko];
#pragma unroll
        for (int mt = 0; mt < 4; ++mt) {
            short8 a = *(const short8*)&Al[(mt * 16 + n) * LSTR + ko];
            acc[mt][0] = __builtin_amdgcn_mfma_f32_16x16x32_bf16(a, b0, acc[mt][0], 0, 0, 0);
            acc[mt][1] = __builtin_amdgcn_mfma_f32_16x16x32_bf16(a, b1, acc[mt][1], 0, 0, 0);
        }
    }

    // epilogue: C/D layout col=lane&15, row=(lane>>4)*4+reg
    float b0c = 0.f, b1c = 0.f;
    if (EPI == 1) { b0c = bias[w * 32 + n]; b1c = bias[w * 32 + 16 + n]; }
#pragma unroll
    for (int mt = 0; mt < 4; ++mt) {
#pragma unroll
        for (int reg = 0; reg < 4; ++reg) {
            int r = row0 + mt * 16 + q * 4 + reg;
            if (r < NN) {
                if (EPI == 0) {
                    float sc = dis[r];
                    unsigned short* OB = (unsigned short*)OUTv;
                    OB[(size_t)r * DD + w * 32 + n]      = f2bf(acc[mt][0][reg] * sc);
                    OB[(size_t)r * DD + w * 32 + 16 + n] = f2bf(acc[mt][1][reg] * sc);
                } else {
                    float* OF = (float*)OUTv;
                    OF[(size_t)r * DD + w * 32 + n]      = fmaxf(acc[mt][0][reg] + b0c, 0.f);
                    OF[(size_t)r * DD + w * 32 + 16 + n] = fmaxf(acc[mt][1][reg] + b1c, 0.f);
                }
            }
        }
    }
}
#undef LSTR

// ---------------- fused gather (bf16 HS, 16 neighbors in flight) ----------------
template<int RELU>
__global__ __launch_bounds__(256) void k_gather(const int* __restrict__ rowptr,
                                                const int* __restrict__ csr,
                                                const uint4* __restrict__ HSq,
                                                const float* __restrict__ dis,
                                                const float* __restrict__ bias,
                                                float* __restrict__ OUT,
                                                float* __restrict__ colsum,
                                                float* __restrict__ colsumsq) {
    const int tid = threadIdx.x;
    const int lane = tid & 63;
    const int wid = tid >> 6;
    const int c = lane & 15;
    const int jj = lane >> 4;
    const int gwave = blockIdx.x * 4 + wid;

    float4 bia0 = ((const float4*)bias)[2 * c];
    float4 bia1 = ((const float4*)bias)[2 * c + 1];
    float sum[8], sq[8];
#pragma unroll
    for (int t = 0; t < 8; ++t) { sum[t] = 0.f; sq[t] = 0.f; }

    for (int r = gwave; r < NN; r += 8192) {
        int beg = rowptr[r], end = rowptr[r + 1];
        float a[8];
#pragma unroll
        for (int t = 0; t < 8; ++t) a[t] = 0.f;

        if (jj == 0) {
            uint4 u = HSq[(size_t)r * 16 + c];
            float2 p0 = bf2x2(u.x), p1 = bf2x2(u.y), p2 = bf2x2(u.z), p3 = bf2x2(u.w);
            a[0] += p0.x; a[1] += p0.y; a[2] += p1.x; a[3] += p1.y;
            a[4] += p2.x; a[5] += p2.y; a[6] += p3.x; a[7] += p3.y;
        }

        int e1 = end - 1;
        for (int j = beg; j < end; j += 16) {
            int i0 = j + jj, i1 = j + 4 + jj, i2 = j + 8 + jj, i3 = j + 12 + jj;
            int s0 = csr[min(i0, e1)];
            int s1 = csr[min(i1, e1)];
            int s2 = csr[min(i2, e1)];
            int s3 = csr[min(i3, e1)];
            uint4 v0 = HSq[(size_t)s0 * 16 + c];
            uint4 v1 = HSq[(size_t)s1 * 16 + c];
            uint4 v2 = HSq[(size_t)s2 * 16 + c];
            uint4 v3 = HSq[(size_t)s3 * 16 + c];
            if (i0 < end) {
                float2 p0 = bf2x2(v0.x), p1 = bf2x2(v0.y), p2 = bf2x2(v0.z), p3 = bf2x2(v0.w);
                a[0] += p0.x; a[1] += p0.y; a[2] += p1.x; a[3] += p1.y;
                a[4] += p2.x; a[5] += p2.y; a[6] += p3.x; a[7] += p3.y;
            }
            if (i1 < end) {
                float2 p0 = bf2x2(v1.x), p1 = bf2x2(v1.y), p2 = bf2x2(v1.z), p3 = bf2x2(v1.w);
                a[0] += p0.x; a[1] += p0.y; a[2] += p1.x; a[3] += p1.y;
                a[4] += p2.x; a[5] += p2.y; a[6] += p3.x; a[7] += p3.y;
            }
            if (i2 < end) {
                float2 p0 = bf2x2(v2.x), p1 = bf2x2(v2.y), p2 = bf2x2(v2.z), p3 = bf2x2(v2.w);
                a[0] += p0.x; a[1] += p0.y; a[2] += p1.x; a[3] += p1.y;
                a[4] += p2.x; a[5] += p2.y; a[6] += p3.x; a[7] += p3.y;
            }
            if (i3 < end) {
                float2 p0 = bf2x2(v3.x), p1 = bf2x2(v3.y), p2 = bf2x2(v3.z), p3 = bf2x2(v3.w);
                a[0] += p0.x; a[1] += p0.y; a[2] += p1.x; a[3] += p1.y;
                a[4] += p2.x; a[5] += p2.y; a[6] += p3.x; a[7] += p3.y;
            }
        }

#pragma unroll
        for (int t = 0; t < 8; ++t) {
            a[t] += __shfl_xor(a[t], 16);
            a[t] += __shfl_xor(a[t], 32);
        }

        if (jj == 0) {
            float dr = dis[r];
            float v[8];
            v[0] = fmaf(dr, a[0], bia0.x); v[1] = fmaf(dr, a[1], bia0.y);
            v[2] = fmaf(dr, a[2], bia0.z); v[3] = fmaf(dr, a[3], bia0.w);
            v[4] = fmaf(dr, a[4], bia1.x); v[5] = fmaf(dr, a[5], bia1.y);
            v[6] = fmaf(dr, a[6], bia1.z); v[7] = fmaf(dr, a[7], bia1.w);
            if (RELU) {
#pragma unroll
                for (int t = 0; t < 8; ++t) v[t] = fmaxf(v[t], 0.f);
            }
            float* op = OUT + (size_t)r * DD + c * 8;
            *(float4*)op       = make_float4(v[0], v[1], v[2], v[3]);
            *(float4*)(op + 4) = make_float4(v[4], v[5], v[6], v[7]);
#pragma unroll
            for (int t = 0; t < 8; ++t) { sum[t] += v[t]; sq[t] += v[t] * v[t]; }
        }
    }

    __shared__ float redS[4][16][8];
    __shared__ float redQ[4][16][8];
    if (jj == 0) {
#pragma unroll
        for (int t = 0; t < 8; ++t) { redS[wid][c][t] = sum[t]; redQ[wid][c][t] = sq[t]; }
    }
    __syncthreads();
    if (tid < 128) {
        int ci = tid >> 3, ct = tid & 7;
        float S = (redS[0][ci][ct] + redS[1][ci][ct]) + (redS[2][ci][ct] + redS[3][ci][ct]);
        float Q = (redQ[0][ci][ct] + redQ[1][ci][ct]) + (redQ[2][ci][ct] + redQ[3][ci][ct]);
        atomicAdd(&colsum[tid], S);
        atomicAdd(&colsumsq[tid], Q);
    }
}

// ---------------- head ----------------
__global__ __launch_bounds__(256) void k_head(const float* __restrict__ H,
                                              const float* __restrict__ ow,
                                              const float* __restrict__ ob,
                                              float* __restrict__ out) {
    int r = blockIdx.x * 4 + (threadIdx.x >> 6);
    if (r >= NN) return;
    int lane = threadIdx.x & 63;
    float2 h = ((const float2*)(H + (size_t)r * DD))[lane];
    float sum = h.x * ow[lane * 2] + h.y * ow[lane * 2 + 1];
#pragma unroll
    for (int off = 32; off > 0; off >>= 1) sum += __shfl_down(sum, off);
    if (lane == 0) {
        float z = sum + ob[0];
        out[r] = 1.f / (1.f + expf(-z));
    }
}

extern "C" void kernel_launch(void* const* d_in, const int* in_sizes, int n_in,
                              void* d_out, int out_size, void* d_ws, size_t ws_size,
                              hipStream_t stream) {
    const float* x      = (const float*)d_in[0];
    const int*   ei     = (const int*)d_in[1];
    const float* conv_w = (const float*)d_in[2];
    const float* conv_b = (const float*)d_in[3];
    const float* bn_g   = (const float*)d_in[4];
    const float* bn_b   = (const float*)d_in[5];
    const float* mlp_w  = (const float*)d_in[6];
    const float* mlp_b  = (const float*)d_in[7];
    const float* out_w  = (const float*)d_in[8];
    const float* out_b  = (const float*)d_in[9];
    float* out = (float*)d_out;

    const size_t ND4 = (size_t)NN * DD * 4;   // 25,600,000 B
    char* ws = (char*)d_ws;
    size_t off = 0;
    float* B0      = (float*)(ws + off); off += ND4;            // fp32 features
    uint4* B1b     = (uint4*)(ws + off); off += ND4 / 2;        // bf16 HS (12.8MB)
    float* B1f     = (float*)(ws + off); off += ND4;            // fp32 mlp hidden
    float* dis     = (float*)(ws + off); off += 204800;
    int*   deg     = (int*)  (ws + off); off += 204800;
    int*   rowptr  = (int*)  (ws + off); off += 204804 + 60;
    int*   cursor  = (int*)  (ws + off); off += 204800;
    int*   bsum    = (int*)  (ws + off); off += 1024;
    int*   boff    = (int*)  (ws + off); off += 1024;
    float* cs      = (float*)(ws + off); off += 512;
    float* css     = (float*)(ws + off); off += 512;
    float* bnsc    = (float*)(ws + off); off += 512;
    float* bnsh    = (float*)(ws + off); off += 512;
    unsigned short* Wtb = (unsigned short*)(ws + off); off += 5 * 16384 * 2;  // 160KB
    int*   csr     = (int*)  (ws + off); off += (size_t)EE * 4;
    // total ≈ 68.4 MB

    const int gemm_grid = (NN + 63) / 64;     // 782
    const int nscan = (NN + 255) / 256;       // 196
    const int gather_grid = 2048;             // 8192 waves

    // ---- CSR build + weight prep ----
    hipMemsetAsync(deg, 0, NN * sizeof(int), stream);
    k_deg<<<(EE + 255) / 256, 256, 0, stream>>>(ei, deg);
    k_dis<<<(NN + 255) / 256, 256, 0, stream>>>(deg, dis);
    k_scan_block<<<nscan, 256, 0, stream>>>(deg, cursor, bsum);
    k_scan_top<<<1, 256, 0, stream>>>(bsum, boff, rowptr + NN, nscan);
    k_scan_final<<<nscan, 256, 0, stream>>>(deg, cursor, boff, rowptr, cursor);
    k_fill<<<(EE + 255) / 256, 256, 0, stream>>>(ei, cursor, csr);
    k_wprep<<<320, 256, 0, stream>>>(conv_w, mlp_w, Wtb);

    // ---- layer 0 ----
    k_gemm_mfma<0, 0><<<gemm_grid, 256, 0, stream>>>(x, Wtb, nullptr, dis, nullptr, nullptr, B1b);
    hipMemsetAsync(cs, 0, 2 * DD * sizeof(float), stream);
    k_gather<0><<<gather_grid, 256, 0, stream>>>(rowptr, csr, B1b, dis, conv_b, B0, cs, css);
    k_bnprep<<<1, 128, 0, stream>>>(cs, css, bn_g, bn_b, bnsc, bnsh);

    // ---- layer 1 ----
    k_gemm_mfma<1, 0><<<gemm_grid, 256, 0, stream>>>(B0, Wtb + 16384, nullptr, dis, bnsc, bnsh, B1b);
    hipMemsetAsync(cs, 0, 2 * DD * sizeof(float), stream);
    k_gather<0><<<gather_grid, 256, 0, stream>>>(rowptr, csr, B1b, dis, conv_b + DD, B0, cs, css);
    k_bnprep<<<1, 128, 0, stream>>>(cs, css, bn_g + DD, bn_b + DD, bnsc, bnsh);

    // ---- layer 2 ----
    k_gemm_mfma<1, 0><<<gemm_grid, 256, 0, stream>>>(B0, Wtb + 2 * 16384, nullptr, dis, bnsc, bnsh, B1b);
    hipMemsetAsync(cs, 0, 2 * DD * sizeof(float), stream);
    k_gather<1><<<gather_grid, 256, 0, stream>>>(rowptr, csr, B1b, dis, conv_b + 2 * DD, B0, cs, css);
    k_bnprep<<<1, 128, 0, stream>>>(cs, css, bn_g + DD, bn_b + DD, bnsc, bnsh);

    // ---- MLP head ----
    k_gemm_mfma<2, 1><<<gemm_grid, 256, 0, stream>>>(B0, Wtb + 3 * 16384, mlp_b, dis, bnsc, bnsh, B1f);
    k_gemm_mfma<0, 1><<<gemm_grid, 256, 0, stream>>>(B1f, Wtb + 4 * 16384, mlp_b + DD, dis, nullptr, nullptr, B0);
    k_head<<<(NN + 3) / 4, 256, 0, stream>>>(B0, out_w, out_b, out);
}

// Round 11
// 510.625 us; speedup vs baseline: 1.6912x; 1.0737x over previous
//
#include <hip/hip_runtime.h>
#include <hip/hip_bf16.h>

#define NN 50000
#define EE 800000
#define DD 128

typedef __attribute__((ext_vector_type(8))) short short8;
typedef __attribute__((ext_vector_type(4))) float floatx4;

__device__ __forceinline__ unsigned short f2bf(float f) {   // RNE
    unsigned int x = __float_as_uint(f);
    unsigned int r = x + 0x7fffu + ((x >> 16) & 1u);
    return (unsigned short)(r >> 16);
}
__device__ __forceinline__ float2 bf2x2(unsigned int u) {   // [lo,hi] bf16 pair
    return make_float2(__uint_as_float(u << 16), __uint_as_float(u & 0xffff0000u));
}

// ---------------- degree (guarded) ----------------
__global__ void k_deg(const int* __restrict__ ei, int* __restrict__ deg) {
    int e = blockIdx.x * 256 + threadIdx.x;
    if (e < EE) {
        int d = ei[EE + e];
        if (d >= 0 && d < NN) atomicAdd(&deg[d], 1);
    }
}

// ---------------- CSR scan stage 1: per-block inclusive scan ----------------
__global__ void k_scan_block(const int* __restrict__ deg, int* __restrict__ scanned,
                             int* __restrict__ blocksum) {
    __shared__ int lds[256];
    int t = threadIdx.x;
    int i = blockIdx.x * 256 + t;
    int v = (i < NN) ? deg[i] : 0;
    lds[t] = v;
    __syncthreads();
    for (int off = 1; off < 256; off <<= 1) {
        int add = (t >= off) ? lds[t - off] : 0;
        __syncthreads();
        lds[t] += add;
        __syncthreads();
    }
    if (i < NN) scanned[i] = lds[t];
    if (t == 255) blocksum[blockIdx.x] = lds[255];
}

// ---------------- CSR scan stage 2 (fused top-scan + final + dis) ----------------
// Each block redundantly scans the <=256 block sums, takes its exclusive offset,
// emits rowptr/cursor, and computes dis. Block 0 writes rowptr[NN].
__global__ void k_scan_final(const int* __restrict__ deg, const int* __restrict__ scanned,
                             const int* __restrict__ blocksum, int nb,
                             int* __restrict__ rowptr, int* __restrict__ cursor,
                             float* __restrict__ dis) {
    __shared__ int lds[256];
    int t = threadIdx.x;
    int v = (t < nb) ? blocksum[t] : 0;
    lds[t] = v;
    __syncthreads();
    for (int off = 1; off < 256; off <<= 1) {
        int add = (t >= off) ? lds[t - off] : 0;
        __syncthreads();
        lds[t] += add;
        __syncthreads();
    }
    int boff = (blockIdx.x == 0) ? 0 : lds[blockIdx.x - 1];
    if (blockIdx.x == 0 && t == 0) rowptr[NN] = lds[nb - 1];
    int i = blockIdx.x * 256 + t;
    if (i < NN) {
        int rv = scanned[i] - deg[i] + boff;
        rowptr[i] = rv;
        cursor[i] = rv;
        dis[i] = rsqrtf((float)deg[i] + 1.0f);
    }
}

__global__ void k_fill(const int* __restrict__ ei, int* __restrict__ cursor,
                       int* __restrict__ csr) {
    int e = blockIdx.x * 256 + threadIdx.x;
    if (e < EE) {
        int s = ei[e];
        int d = ei[EE + e];
        if ((unsigned)s < (unsigned)NN && (unsigned)d < (unsigned)NN) {
            int pos = atomicAdd(&cursor[d], 1);
            csr[pos] = s;
        }
    }
}

// ---------------- W prep: fp32 [k][c] -> bf16 transposed [c][k], all 5 mats ----
__global__ void k_wprep(const float* __restrict__ conv_w, const float* __restrict__ mlp_w,
                        unsigned short* __restrict__ Wt) {
    int g = blockIdx.x * 256 + threadIdx.x;        // [0, 81920)
    int mat = g >> 14;
    int rem = g & 16383;
    int k = rem >> 7, c = rem & 127;
    const float* src = (mat < 3) ? (conv_w + mat * 16384) : (mlp_w + (mat - 3) * 16384);
    Wt[mat * 16384 + c * 128 + k] = f2bf(src[k * 128 + c]);
}

// ---------------- MFMA GEMM: OUT = pro(IN) @ W (+epilogue) ----------------
// PRO: 0=none, 1=BN+relu on A while staging, 2=BN only (bnprep inlined from cs/css)
// EPI: 0=row-scale by dis -> bf16 out (conv HS)
//      1=+bias,relu -> fp32 out (mlp hidden)
//      2=+bias,relu, dot out_w, +out_b, sigmoid -> out[r] (fused head)
#define LSTR 136
template<int PRO, int EPI>
__global__ __launch_bounds__(256) void k_gemm_mfma(const float* __restrict__ IN,
                                                   const unsigned short* __restrict__ Wt,
                                                   const float* __restrict__ bias,
                                                   const float* __restrict__ dis,
                                                   const float* __restrict__ cs,
                                                   const float* __restrict__ css,
                                                   const float* __restrict__ gamma,
                                                   const float* __restrict__ beta,
                                                   const float* __restrict__ ow,
                                                   const float* __restrict__ ob,
                                                   void* __restrict__ OUTv) {
    __shared__ unsigned short Wl[128 * LSTR];   // [c][k] 34.8KB
    __shared__ unsigned short Al[64 * LSTR];    // [r][k] 17.4KB
    __shared__ float bnscL[128], bnshL[128];
    __shared__ float redH[4][64];
    const int tid = threadIdx.x;
    const int lane = tid & 63;
    const int w = tid >> 6;
    const int row0 = blockIdx.x * 64;

    if (PRO) {
        if (tid < 128) {
            const float invn = 1.f / (float)NN;
            float mean = cs[tid] * invn;
            float var = css[tid] * invn - mean * mean;
            float sc = gamma[tid] * rsqrtf(fmaxf(var, 0.f) + 1e-5f);
            bnscL[tid] = sc;
            bnshL[tid] = beta[tid] - mean * sc;
        }
        __syncthreads();
    }

    // stage Wt: 2048 granules of 16B; 16 granules per 128-elem row
    {
        const uint4* src = (const uint4*)Wt;
#pragma unroll
        for (int i = 0; i < 8; ++i) {
            int g = tid + 256 * i;
            int c = g >> 4, gi = g & 15;
            *(uint4*)&Wl[c * LSTR + gi * 8] = src[g];
        }
    }
    // stage A: thread -> row tid>>2, k-quarter (tid&3)*32
    {
        int r = tid >> 2, kq = (tid & 3) * 32;
        int gr = row0 + r;
        unsigned short tmp[32];
#pragma unroll
        for (int i = 0; i < 8; ++i) {
            float4 v = make_float4(0.f, 0.f, 0.f, 0.f);
            if (gr < NN) v = *(const float4*)&IN[(size_t)gr * DD + kq + i * 4];
            if (PRO) {
                float4 sc = *(const float4*)&bnscL[kq + i * 4];
                float4 sh = *(const float4*)&bnshL[kq + i * 4];
                v.x = fmaf(v.x, sc.x, sh.x);
                v.y = fmaf(v.y, sc.y, sh.y);
                v.z = fmaf(v.z, sc.z, sh.z);
                v.w = fmaf(v.w, sc.w, sh.w);
                if (PRO == 1) {
                    v.x = fmaxf(v.x, 0.f); v.y = fmaxf(v.y, 0.f);
                    v.z = fmaxf(v.z, 0.f); v.w = fmaxf(v.w, 0.f);
                }
            }
            tmp[i * 4 + 0] = f2bf(v.x); tmp[i * 4 + 1] = f2bf(v.y);
            tmp[i * 4 + 2] = f2bf(v.z); tmp[i * 4 + 3] = f2bf(v.w);
        }
#pragma unroll
        for (int j = 0; j < 4; ++j)
            *(uint4*)&Al[r * LSTR + kq + j * 8] = ((uint4*)tmp)[j];
    }
    __syncthreads();

    const int n = lane & 15, q = lane >> 4;
    floatx4 acc[4][2];
#pragma unroll
    for (int mt = 0; mt < 4; ++mt)
#pragma unroll
        for (int nt = 0; nt < 2; ++nt)
            acc[mt][nt] = (floatx4){0.f, 0.f, 0.f, 0.f};

#pragma unroll
    for (int kk = 0; kk < 4; ++kk) {
        int ko = kk * 32 + q * 8;
        short8 b0 = *(const short8*)&Wl[(w * 32 + n) * LSTR + ko];
        short8 b1 = *(const short8*)&Wl[(w * 32 + 16 + n) * LSTR + ko];
#pragma unroll
        for (int mt = 0; mt < 4; ++mt) {
            short8 a = *(const short8*)&Al[(mt * 16 + n) * LSTR + ko];
            acc[mt][0] = __builtin_amdgcn_mfma_f32_16x16x32_bf16(a, b0, acc[mt][0], 0, 0, 0);
            acc[mt][1] = __builtin_amdgcn_mfma_f32_16x16x32_bf16(a, b1, acc[mt][1], 0, 0, 0);
        }
    }

    // epilogue: C/D layout col=lane&15, row=(lane>>4)*4+reg
    if (EPI == 0) {
#pragma unroll
        for (int mt = 0; mt < 4; ++mt) {
#pragma unroll
            for (int reg = 0; reg < 4; ++reg) {
                int r = row0 + mt * 16 + q * 4 + reg;
                if (r < NN) {
                    float sc = dis[r];
                    unsigned short* OB = (unsigned short*)OUTv;
                    OB[(size_t)r * DD + w * 32 + n]      = f2bf(acc[mt][0][reg] * sc);
                    OB[(size_t)r * DD + w * 32 + 16 + n] = f2bf(acc[mt][1][reg] * sc);
                }
            }
        }
    } else if (EPI == 1) {
        float b0c = bias[w * 32 + n], b1c = bias[w * 32 + 16 + n];
#pragma unroll
        for (int mt = 0; mt < 4; ++mt) {
#pragma unroll
            for (int reg = 0; reg < 4; ++reg) {
                int r = row0 + mt * 16 + q * 4 + reg;
                if (r < NN) {
                    float* OF = (float*)OUTv;
                    OF[(size_t)r * DD + w * 32 + n]      = fmaxf(acc[mt][0][reg] + b0c, 0.f);
                    OF[(size_t)r * DD + w * 32 + 16 + n] = fmaxf(acc[mt][1][reg] + b1c, 0.f);
                }
            }
        }
    } else {
        // fused head: z = relu(acc + bias) . ow ; out = sigmoid(z + ob)
        float b0c = bias[w * 32 + n], b1c = bias[w * 32 + 16 + n];
        float w0c = ow[w * 32 + n],  w1c = ow[w * 32 + 16 + n];
#pragma unroll
        for (int mt = 0; mt < 4; ++mt) {
#pragma unroll
            for (int reg = 0; reg < 4; ++reg) {
                float h0 = fmaxf(acc[mt][0][reg] + b0c, 0.f);
                float h1 = fmaxf(acc[mt][1][reg] + b1c, 0.f);
                float p = fmaf(h0, w0c, h1 * w1c);
                // reduce over the 16 n-lanes (same q)
                p += __shfl_xor(p, 1);
                p += __shfl_xor(p, 2);
                p += __shfl_xor(p, 4);
                p += __shfl_xor(p, 8);
                if (n == 0) redH[w][mt * 16 + q * 4 + reg] = p;
            }
        }
        __syncthreads();
        if (tid < 64) {
            int r = row0 + tid;
            if (r < NN) {
                float z = (redH[0][tid] + redH[1][tid]) + (redH[2][tid] + redH[3][tid]) + ob[0];
                ((float*)OUTv)[r] = 1.f / (1.f + expf(-z));
            }
        }
    }
}
#undef LSTR

// ---------------- fused gather (bf16 HS, 16 neighbors in flight) ----------------
template<int RELU>
__global__ __launch_bounds__(256) void k_gather(const int* __restrict__ rowptr,
                                                const int* __restrict__ csr,
                                                const uint4* __restrict__ HSq,
                                                const float* __restrict__ dis,
                                                const float* __restrict__ bias,
                                                float* __restrict__ OUT,
                                                float* __restrict__ colsum,
                                                float* __restrict__ colsumsq) {
    const int tid = threadIdx.x;
    const int lane = tid & 63;
    const int wid = tid >> 6;
    const int c = lane & 15;
    const int jj = lane >> 4;
    const int gwave = blockIdx.x * 4 + wid;

    float4 bia0 = ((const float4*)bias)[2 * c];
    float4 bia1 = ((const float4*)bias)[2 * c + 1];
    float sum[8], sq[8];
#pragma unroll
    for (int t = 0; t < 8; ++t) { sum[t] = 0.f; sq[t] = 0.f; }

    for (int r = gwave; r < NN; r += 8192) {
        int beg = rowptr[r], end = rowptr[r + 1];
        float a[8];
#pragma unroll
        for (int t = 0; t < 8; ++t) a[t] = 0.f;

        if (jj == 0) {
            uint4 u = HSq[(size_t)r * 16 + c];
            float2 p0 = bf2x2(u.x), p1 = bf2x2(u.y), p2 = bf2x2(u.z), p3 = bf2x2(u.w);
            a[0] += p0.x; a[1] += p0.y; a[2] += p1.x; a[3] += p1.y;
            a[4] += p2.x; a[5] += p2.y; a[6] += p3.x; a[7] += p3.y;
        }

        int e1 = end - 1;
        for (int j = beg; j < end; j += 16) {
            int i0 = j + jj, i1 = j + 4 + jj, i2 = j + 8 + jj, i3 = j + 12 + jj;
            int s0 = csr[min(i0, e1)];
            int s1 = csr[min(i1, e1)];
            int s2 = csr[min(i2, e1)];
            int s3 = csr[min(i3, e1)];
            uint4 v0 = HSq[(size_t)s0 * 16 + c];
            uint4 v1 = HSq[(size_t)s1 * 16 + c];
            uint4 v2 = HSq[(size_t)s2 * 16 + c];
            uint4 v3 = HSq[(size_t)s3 * 16 + c];
            if (i0 < end) {
                float2 p0 = bf2x2(v0.x), p1 = bf2x2(v0.y), p2 = bf2x2(v0.z), p3 = bf2x2(v0.w);
                a[0] += p0.x; a[1] += p0.y; a[2] += p1.x; a[3] += p1.y;
                a[4] += p2.x; a[5] += p2.y; a[6] += p3.x; a[7] += p3.y;
            }
            if (i1 < end) {
                float2 p0 = bf2x2(v1.x), p1 = bf2x2(v1.y), p2 = bf2x2(v1.z), p3 = bf2x2(v1.w);
                a[0] += p0.x; a[1] += p0.y; a[2] += p1.x; a[3] += p1.y;
                a[4] += p2.x; a[5] += p2.y; a[6] += p3.x; a[7] += p3.y;
            }
            if (i2 < end) {
                float2 p0 = bf2x2(v2.x), p1 = bf2x2(v2.y), p2 = bf2x2(v2.z), p3 = bf2x2(v2.w);
                a[0] += p0.x; a[1] += p0.y; a[2] += p1.x; a[3] += p1.y;
                a[4] += p2.x; a[5] += p2.y; a[6] += p3.x; a[7] += p3.y;
            }
            if (i3 < end) {
                float2 p0 = bf2x2(v3.x), p1 = bf2x2(v3.y), p2 = bf2x2(v3.z), p3 = bf2x2(v3.w);
                a[0] += p0.x; a[1] += p0.y; a[2] += p1.x; a[3] += p1.y;
                a[4] += p2.x; a[5] += p2.y; a[6] += p3.x; a[7] += p3.y;
            }
        }

#pragma unroll
        for (int t = 0; t < 8; ++t) {
            a[t] += __shfl_xor(a[t], 16);
            a[t] += __shfl_xor(a[t], 32);
        }

        if (jj == 0) {
            float dr = dis[r];
            float v[8];
            v[0] = fmaf(dr, a[0], bia0.x); v[1] = fmaf(dr, a[1], bia0.y);
            v[2] = fmaf(dr, a[2], bia0.z); v[3] = fmaf(dr, a[3], bia0.w);
            v[4] = fmaf(dr, a[4], bia1.x); v[5] = fmaf(dr, a[5], bia1.y);
            v[6] = fmaf(dr, a[6], bia1.z); v[7] = fmaf(dr, a[7], bia1.w);
            if (RELU) {
#pragma unroll
                for (int t = 0; t < 8; ++t) v[t] = fmaxf(v[t], 0.f);
            }
            float* op = OUT + (size_t)r * DD + c * 8;
            *(float4*)op       = make_float4(v[0], v[1], v[2], v[3]);
            *(float4*)(op + 4) = make_float4(v[4], v[5], v[6], v[7]);
#pragma unroll
            for (int t = 0; t < 8; ++t) { sum[t] += v[t]; sq[t] += v[t] * v[t]; }
        }
    }

    __shared__ float redS[4][16][8];
    __shared__ float redQ[4][16][8];
    if (jj == 0) {
#pragma unroll
        for (int t = 0; t < 8; ++t) { redS[wid][c][t] = sum[t]; redQ[wid][c][t] = sq[t]; }
    }
    __syncthreads();
    if (tid < 128) {
        int ci = tid >> 3, ct = tid & 7;
        float S = (redS[0][ci][ct] + redS[1][ci][ct]) + (redS[2][ci][ct] + redS[3][ci][ct]);
        float Q = (redQ[0][ci][ct] + redQ[1][ci][ct]) + (redQ[2][ci][ct] + redQ[3][ci][ct]);
        atomicAdd(&colsum[tid], S);
        atomicAdd(&colsumsq[tid], Q);
    }
}

extern "C" void kernel_launch(void* const* d_in, const int* in_sizes, int n_in,
                              void* d_out, int out_size, void* d_ws, size_t ws_size,
                              hipStream_t stream) {
    const float* x      = (const float*)d_in[0];
    const int*   ei     = (const int*)d_in[1];
    const float* conv_w = (const float*)d_in[2];
    const float* conv_b = (const float*)d_in[3];
    const float* bn_g   = (const float*)d_in[4];
    const float* bn_b   = (const float*)d_in[5];
    const float* mlp_w  = (const float*)d_in[6];
    const float* mlp_b  = (const float*)d_in[7];
    const float* out_w  = (const float*)d_in[8];
    const float* out_b  = (const float*)d_in[9];
    float* out = (float*)d_out;

    const size_t ND4 = (size_t)NN * DD * 4;   // 25,600,000 B
    char* ws = (char*)d_ws;
    size_t off = 0;
    float* B0      = (float*)(ws + off); off += ND4;            // fp32 features
    uint4* B1b     = (uint4*)(ws + off); off += ND4 / 2;        // bf16 HS (12.8MB)
    float* B1f     = (float*)(ws + off); off += ND4;            // fp32 mlp hidden
    int*   deg     = (int*)  (ws + off); off += 204800;         // zeroed region start
    float* cs3     = (float*)(ws + off); off += 3 * 512;        //   cs[3][128]
    float* css3    = (float*)(ws + off); off += 3 * 512;        //   css[3][128]  (zeroed region end)
    float* dis     = (float*)(ws + off); off += 204800;
    int*   rowptr  = (int*)  (ws + off); off += 204804 + 60;
    int*   cursor  = (int*)  (ws + off); off += 204800;
    int*   bsum    = (int*)  (ws + off); off += 1024;
    unsigned short* Wtb = (unsigned short*)(ws + off); off += 5 * 16384 * 2;  // 160KB
    int*   csr     = (int*)  (ws + off); off += (size_t)EE * 4;
    // total ≈ 68.4 MB

    const int gemm_grid = (NN + 63) / 64;     // 782
    const int nscan = (NN + 255) / 256;       // 196
    const int gather_grid = 2048;             // 8192 waves

    // ---- single memset: deg + all layer stats ----
    hipMemsetAsync(deg, 0, 204800 + 6 * 512, stream);

    // ---- CSR build + weight prep (5 kernels) ----
    k_deg<<<(EE + 255) / 256, 256, 0, stream>>>(ei, deg);
    k_scan_block<<<nscan, 256, 0, stream>>>(deg, cursor, bsum);
    k_scan_final<<<nscan, 256, 0, stream>>>(deg, cursor, bsum, nscan, rowptr, cursor, dis);
    k_fill<<<(EE + 255) / 256, 256, 0, stream>>>(ei, cursor, csr);
    k_wprep<<<320, 256, 0, stream>>>(conv_w, mlp_w, Wtb);

    // ---- layer 0 ----
    k_gemm_mfma<0, 0><<<gemm_grid, 256, 0, stream>>>(x, Wtb, nullptr, dis,
        nullptr, nullptr, nullptr, nullptr, nullptr, nullptr, B1b);
    k_gather<0><<<gather_grid, 256, 0, stream>>>(rowptr, csr, B1b, dis, conv_b, B0, cs3, css3);

    // ---- layer 1 (BN stats 0, gamma/beta 0) ----
    k_gemm_mfma<1, 0><<<gemm_grid, 256, 0, stream>>>(B0, Wtb + 16384, nullptr, dis,
        cs3, css3, bn_g, bn_b, nullptr, nullptr, B1b);
    k_gather<0><<<gather_grid, 256, 0, stream>>>(rowptr, csr, B1b, dis, conv_b + DD, B0, cs3 + 128, css3 + 128);

    // ---- layer 2 (BN stats 1, gamma/beta 1) ----
    k_gemm_mfma<1, 0><<<gemm_grid, 256, 0, stream>>>(B0, Wtb + 2 * 16384, nullptr, dis,
        cs3 + 128, css3 + 128, bn_g + DD, bn_b + DD, nullptr, nullptr, B1b);
    k_gather<1><<<gather_grid, 256, 0, stream>>>(rowptr, csr, B1b, dis, conv_b + 2 * DD, B0, cs3 + 256, css3 + 256);

    // ---- MLP: BN(stats 2, gamma/beta 1) -> gemm relu -> gemm relu + head ----
    k_gemm_mfma<2, 1><<<gemm_grid, 256, 0, stream>>>(B0, Wtb + 3 * 16384, mlp_b, dis,
        cs3 + 256, css3 + 256, bn_g + DD, bn_b + DD, nullptr, nullptr, B1f);
    k_gemm_mfma<0, 2><<<gemm_grid, 256, 0, stream>>>(B1f, Wtb + 4 * 16384, mlp_b + DD, dis,
        nullptr, nullptr, nullptr, nullptr, out_w, out_b, out);
}

// Round 12
// 491.229 us; speedup vs baseline: 1.7580x; 1.0395x over previous
//
#include <hip/hip_runtime.h>
#include <hip/hip_bf16.h>

#define NN 50000
#define EE 800000
#define DD 128

typedef __attribute__((ext_vector_type(8))) short short8;
typedef __attribute__((ext_vector_type(4))) float floatx4;

__device__ __forceinline__ unsigned short f2bf(float f) {   // RNE
    unsigned int x = __float_as_uint(f);
    unsigned int r = x + 0x7fffu + ((x >> 16) & 1u);
    return (unsigned short)(r >> 16);
}
__device__ __forceinline__ float2 bf2x2(unsigned int u) {   // [lo,hi] bf16 pair
    return make_float2(__uint_as_float(u << 16), __uint_as_float(u & 0xffff0000u));
}

// ---------------- degree (guarded) ----------------
__global__ void k_deg(const int* __restrict__ ei, int* __restrict__ deg) {
    int e = blockIdx.x * 256 + threadIdx.x;
    if (e < EE) {
        int d = ei[EE + e];
        if (d >= 0 && d < NN) atomicAdd(&deg[d], 1);
    }
}

// ---------------- CSR scan stage 1 ----------------
__global__ void k_scan_block(const int* __restrict__ deg, int* __restrict__ scanned,
                             int* __restrict__ blocksum) {
    __shared__ int lds[256];
    int t = threadIdx.x;
    int i = blockIdx.x * 256 + t;
    int v = (i < NN) ? deg[i] : 0;
    lds[t] = v;
    __syncthreads();
    for (int off = 1; off < 256; off <<= 1) {
        int add = (t >= off) ? lds[t - off] : 0;
        __syncthreads();
        lds[t] += add;
        __syncthreads();
    }
    if (i < NN) scanned[i] = lds[t];
    if (t == 255) blocksum[blockIdx.x] = lds[255];
}

// ---------------- CSR scan stage 2 (top-scan + final + dis) ----------------
__global__ void k_scan_final(const int* __restrict__ deg, const int* __restrict__ scanned,
                             const int* __restrict__ blocksum, int nb,
                             int* __restrict__ rowptr, int* __restrict__ cursor,
                             float* __restrict__ dis) {
    __shared__ int lds[256];
    int t = threadIdx.x;
    int v = (t < nb) ? blocksum[t] : 0;
    lds[t] = v;
    __syncthreads();
    for (int off = 1; off < 256; off <<= 1) {
        int add = (t >= off) ? lds[t - off] : 0;
        __syncthreads();
        lds[t] += add;
        __syncthreads();
    }
    int boff = (blockIdx.x == 0) ? 0 : lds[blockIdx.x - 1];
    if (blockIdx.x == 0 && t == 0) rowptr[NN] = lds[nb - 1];
    int i = blockIdx.x * 256 + t;
    if (i < NN) {
        int rv = scanned[i] - deg[i] + boff;
        rowptr[i] = rv;
        cursor[i] = rv;
        dis[i] = rsqrtf((float)deg[i] + 1.0f);
    }
}

__global__ void k_fill(const int* __restrict__ ei, int* __restrict__ cursor,
                       int* __restrict__ csr) {
    int e = blockIdx.x * 256 + threadIdx.x;
    if (e < EE) {
        int s = ei[e];
        int d = ei[EE + e];
        if ((unsigned)s < (unsigned)NN && (unsigned)d < (unsigned)NN) {
            int pos = atomicAdd(&cursor[d], 1);
            csr[pos] = s;
        }
    }
}

// ---------------- W prep: fp32 [k][c] -> bf16 FRAGMENT ORDER, all 5 mats ----
// dst short index within mat: (((w*2+nt)*4+kk)*64 + q*16 + n)*8 + j
// src: W[k=kk*32+q*8+j][c=w*32+nt*16+n]
__global__ void k_wprep(const float* __restrict__ conv_w, const float* __restrict__ mlp_w,
                        unsigned short* __restrict__ Wf) {
    int g = blockIdx.x * 256 + threadIdx.x;        // [0, 81920)
    int m = g >> 14;
    int idx = g & 16383;
    int j  = idx & 7;
    int n  = (idx >> 3) & 15;
    int q  = (idx >> 7) & 3;
    int kk = (idx >> 9) & 3;
    int nt = (idx >> 11) & 1;
    int w  = (idx >> 12) & 3;
    int k = kk * 32 + q * 8 + j;
    int c = w * 32 + nt * 16 + n;
    const float* src = (m < 3) ? (conv_w + m * 16384) : (mlp_w + (m - 3) * 16384);
    Wf[g] = f2bf(src[k * 128 + c]);
}

// ---------------- conv MFMA GEMM: HS = pro(IN) @ W * dis -> bf16 ----------------
// PRO: 0=none, 1=BN+relu on A while staging (bnprep inlined from cs/css)
// B-fragments read directly from Wf (fragment-ordered, L1/L2-hot).
#define LSTR 136
template<int PRO>
__global__ __launch_bounds__(256) void k_gemm_conv(const float* __restrict__ IN,
                                                   const unsigned short* __restrict__ Wf,
                                                   const float* __restrict__ dis,
                                                   const float* __restrict__ cs,
                                                   const float* __restrict__ css,
                                                   const float* __restrict__ gamma,
                                                   const float* __restrict__ beta,
                                                   unsigned short* __restrict__ OUT) {
    __shared__ unsigned short Al[64 * LSTR];    // [r][k] 17.4KB
    __shared__ float bnscL[128], bnshL[128];
    const int tid = threadIdx.x;
    const int lane = tid & 63;
    const int w = tid >> 6;
    const int row0 = blockIdx.x * 64;

    if (PRO) {
        if (tid < 128) {
            const float invn = 1.f / (float)NN;
            float mean = cs[tid] * invn;
            float var = css[tid] * invn - mean * mean;
            float sc = gamma[tid] * rsqrtf(fmaxf(var, 0.f) + 1e-5f);
            bnscL[tid] = sc;
            bnshL[tid] = beta[tid] - mean * sc;
        }
        __syncthreads();
    }

    // B fragments: 8 coalesced 16B loads (nt in {0,1} x kk in {0..3})
    short8 bf[2][4];
    {
        const uint4* Wq = (const uint4*)Wf;
#pragma unroll
        for (int nt = 0; nt < 2; ++nt)
#pragma unroll
            for (int kk = 0; kk < 4; ++kk) {
                uint4 u = Wq[((w * 2 + nt) * 4 + kk) * 64 + lane];
                bf[nt][kk] = *(short8*)&u;
            }
    }

    // stage A: thread -> row tid>>2, k-quarter (tid&3)*32
    {
        int r = tid >> 2, kq = (tid & 3) * 32;
        int gr = row0 + r;
        unsigned short tmp[32];
#pragma unroll
        for (int i = 0; i < 8; ++i) {
            float4 v = make_float4(0.f, 0.f, 0.f, 0.f);
            if (gr < NN) v = *(const float4*)&IN[(size_t)gr * DD + kq + i * 4];
            if (PRO) {
                float4 sc = *(const float4*)&bnscL[kq + i * 4];
                float4 sh = *(const float4*)&bnshL[kq + i * 4];
                v.x = fmaf(v.x, sc.x, sh.x);
                v.y = fmaf(v.y, sc.y, sh.y);
                v.z = fmaf(v.z, sc.z, sh.z);
                v.w = fmaf(v.w, sc.w, sh.w);
                v.x = fmaxf(v.x, 0.f); v.y = fmaxf(v.y, 0.f);
                v.z = fmaxf(v.z, 0.f); v.w = fmaxf(v.w, 0.f);
            }
            tmp[i * 4 + 0] = f2bf(v.x); tmp[i * 4 + 1] = f2bf(v.y);
            tmp[i * 4 + 2] = f2bf(v.z); tmp[i * 4 + 3] = f2bf(v.w);
        }
#pragma unroll
        for (int j = 0; j < 4; ++j)
            *(uint4*)&Al[r * LSTR + kq + j * 8] = ((uint4*)tmp)[j];
    }
    __syncthreads();

    const int n = lane & 15, q = lane >> 4;
    floatx4 acc[4][2];
#pragma unroll
    for (int mt = 0; mt < 4; ++mt)
#pragma unroll
        for (int nt = 0; nt < 2; ++nt)
            acc[mt][nt] = (floatx4){0.f, 0.f, 0.f, 0.f};

#pragma unroll
    for (int kk = 0; kk < 4; ++kk) {
        int ko = kk * 32 + q * 8;
#pragma unroll
        for (int mt = 0; mt < 4; ++mt) {
            short8 a = *(const short8*)&Al[(mt * 16 + n) * LSTR + ko];
            acc[mt][0] = __builtin_amdgcn_mfma_f32_16x16x32_bf16(a, bf[0][kk], acc[mt][0], 0, 0, 0);
            acc[mt][1] = __builtin_amdgcn_mfma_f32_16x16x32_bf16(a, bf[1][kk], acc[mt][1], 0, 0, 0);
        }
    }

    // epilogue: C/D layout col=lane&15, row=(lane>>4)*4+reg; *dis -> bf16
#pragma unroll
    for (int mt = 0; mt < 4; ++mt) {
#pragma unroll
        for (int reg = 0; reg < 4; ++reg) {
            int r = row0 + mt * 16 + q * 4 + reg;
            if (r < NN) {
                float sc = dis[r];
                OUT[(size_t)r * DD + w * 32 + n]      = f2bf(acc[mt][0][reg] * sc);
                OUT[(size_t)r * DD + w * 32 + 16 + n] = f2bf(acc[mt][1][reg] * sc);
            }
        }
    }
}

// ---------------- fused MLP: out = sigmoid(relu(relu(BN(H)@W4+b4)@W5+b5).ow+ob) ----
__global__ __launch_bounds__(256) void k_mlp_head(const float* __restrict__ IN,
                                                  const unsigned short* __restrict__ Wf4,
                                                  const unsigned short* __restrict__ Wf5,
                                                  const float* __restrict__ b4,
                                                  const float* __restrict__ b5,
                                                  const float* __restrict__ cs,
                                                  const float* __restrict__ css,
                                                  const float* __restrict__ gamma,
                                                  const float* __restrict__ beta,
                                                  const float* __restrict__ ow,
                                                  const float* __restrict__ ob,
                                                  float* __restrict__ out) {
    __shared__ unsigned short Al[64 * LSTR];    // A tile, then reused as hidden tile
    __shared__ float bnscL[128], bnshL[128];
    __shared__ float redH[4][64];
    const int tid = threadIdx.x;
    const int lane = tid & 63;
    const int w = tid >> 6;
    const int row0 = blockIdx.x * 64;
    const int n = lane & 15, q = lane >> 4;

    if (tid < 128) {
        const float invn = 1.f / (float)NN;
        float mean = cs[tid] * invn;
        float var = css[tid] * invn - mean * mean;
        float sc = gamma[tid] * rsqrtf(fmaxf(var, 0.f) + 1e-5f);
        bnscL[tid] = sc;
        bnshL[tid] = beta[tid] - mean * sc;
    }
    __syncthreads();

    // stage A = BN(IN) (no relu)
    {
        int r = tid >> 2, kq = (tid & 3) * 32;
        int gr = row0 + r;
        unsigned short tmp[32];
#pragma unroll
        for (int i = 0; i < 8; ++i) {
            float4 v = make_float4(0.f, 0.f, 0.f, 0.f);
            if (gr < NN) v = *(const float4*)&IN[(size_t)gr * DD + kq + i * 4];
            float4 sc = *(const float4*)&bnscL[kq + i * 4];
            float4 sh = *(const float4*)&bnshL[kq + i * 4];
            v.x = fmaf(v.x, sc.x, sh.x);
            v.y = fmaf(v.y, sc.y, sh.y);
            v.z = fmaf(v.z, sc.z, sh.z);
            v.w = fmaf(v.w, sc.w, sh.w);
            tmp[i * 4 + 0] = f2bf(v.x); tmp[i * 4 + 1] = f2bf(v.y);
            tmp[i * 4 + 2] = f2bf(v.z); tmp[i * 4 + 3] = f2bf(v.w);
        }
#pragma unroll
        for (int j = 0; j < 4; ++j)
            *(uint4*)&Al[r * LSTR + kq + j * 8] = ((uint4*)tmp)[j];
    }
    __syncthreads();

    // ---- GEMM 1: hidden = relu(A @ W4 + b4) ----
    floatx4 acc[4][2];
#pragma unroll
    for (int mt = 0; mt < 4; ++mt)
#pragma unroll
        for (int nt = 0; nt < 2; ++nt)
            acc[mt][nt] = (floatx4){0.f, 0.f, 0.f, 0.f};
    {
        const uint4* Wq = (const uint4*)Wf4;
#pragma unroll
        for (int kk = 0; kk < 4; ++kk) {
            uint4 u0 = Wq[((w * 2 + 0) * 4 + kk) * 64 + lane];
            uint4 u1 = Wq[((w * 2 + 1) * 4 + kk) * 64 + lane];
            int ko = kk * 32 + q * 8;
#pragma unroll
            for (int mt = 0; mt < 4; ++mt) {
                short8 a = *(const short8*)&Al[(mt * 16 + n) * LSTR + ko];
                acc[mt][0] = __builtin_amdgcn_mfma_f32_16x16x32_bf16(a, *(short8*)&u0, acc[mt][0], 0, 0, 0);
                acc[mt][1] = __builtin_amdgcn_mfma_f32_16x16x32_bf16(a, *(short8*)&u1, acc[mt][1], 0, 0, 0);
            }
        }
    }
    __syncthreads();   // everyone done reading Al

    // write hidden (bf16) into Al: row = mt*16+q*4+reg, cols w*32+n / +16
    {
        float b0c = b4[w * 32 + n], b1c = b4[w * 32 + 16 + n];
#pragma unroll
        for (int mt = 0; mt < 4; ++mt) {
#pragma unroll
            for (int reg = 0; reg < 4; ++reg) {
                int r = mt * 16 + q * 4 + reg;
                Al[r * LSTR + w * 32 + n]      = f2bf(fmaxf(acc[mt][0][reg] + b0c, 0.f));
                Al[r * LSTR + w * 32 + 16 + n] = f2bf(fmaxf(acc[mt][1][reg] + b1c, 0.f));
            }
        }
    }
    __syncthreads();

    // ---- GEMM 2 + head ----
#pragma unroll
    for (int mt = 0; mt < 4; ++mt)
#pragma unroll
        for (int nt = 0; nt < 2; ++nt)
            acc[mt][nt] = (floatx4){0.f, 0.f, 0.f, 0.f};
    {
        const uint4* Wq = (const uint4*)Wf5;
#pragma unroll
        for (int kk = 0; kk < 4; ++kk) {
            uint4 u0 = Wq[((w * 2 + 0) * 4 + kk) * 64 + lane];
            uint4 u1 = Wq[((w * 2 + 1) * 4 + kk) * 64 + lane];
            int ko = kk * 32 + q * 8;
#pragma unroll
            for (int mt = 0; mt < 4; ++mt) {
                short8 a = *(const short8*)&Al[(mt * 16 + n) * LSTR + ko];
                acc[mt][0] = __builtin_amdgcn_mfma_f32_16x16x32_bf16(a, *(short8*)&u0, acc[mt][0], 0, 0, 0);
                acc[mt][1] = __builtin_amdgcn_mfma_f32_16x16x32_bf16(a, *(short8*)&u1, acc[mt][1], 0, 0, 0);
            }
        }
    }
    {
        float b0c = b5[w * 32 + n], b1c = b5[w * 32 + 16 + n];
        float w0c = ow[w * 32 + n], w1c = ow[w * 32 + 16 + n];
#pragma unroll
        for (int mt = 0; mt < 4; ++mt) {
#pragma unroll
            for (int reg = 0; reg < 4; ++reg) {
                float h0 = fmaxf(acc[mt][0][reg] + b0c, 0.f);
                float h1 = fmaxf(acc[mt][1][reg] + b1c, 0.f);
                float p = fmaf(h0, w0c, h1 * w1c);
                p += __shfl_xor(p, 1);
                p += __shfl_xor(p, 2);
                p += __shfl_xor(p, 4);
                p += __shfl_xor(p, 8);
                if (n == 0) redH[w][mt * 16 + q * 4 + reg] = p;
            }
        }
        __syncthreads();
        if (tid < 64) {
            int r = row0 + tid;
            if (r < NN) {
                float z = (redH[0][tid] + redH[1][tid]) + (redH[2][tid] + redH[3][tid]) + ob[0];
                out[r] = 1.f / (1.f + expf(-z));
            }
        }
    }
}
#undef LSTR

// ---------------- fused gather (bf16 HS, 16 neighbors in flight) ----------------
template<int RELU>
__global__ __launch_bounds__(256) void k_gather(const int* __restrict__ rowptr,
                                                const int* __restrict__ csr,
                                                const uint4* __restrict__ HSq,
                                                const float* __restrict__ dis,
                                                const float* __restrict__ bias,
                                                float* __restrict__ OUT,
                                                float* __restrict__ colsum,
                                                float* __restrict__ colsumsq) {
    const int tid = threadIdx.x;
    const int lane = tid & 63;
    const int wid = tid >> 6;
    const int c = lane & 15;
    const int jj = lane >> 4;
    const int gwave = blockIdx.x * 4 + wid;

    float4 bia0 = ((const float4*)bias)[2 * c];
    float4 bia1 = ((const float4*)bias)[2 * c + 1];
    float sum[8], sq[8];
#pragma unroll
    for (int t = 0; t < 8; ++t) { sum[t] = 0.f; sq[t] = 0.f; }

    for (int r = gwave; r < NN; r += 8192) {
        int beg = rowptr[r], end = rowptr[r + 1];
        float a[8];
#pragma unroll
        for (int t = 0; t < 8; ++t) a[t] = 0.f;

        if (jj == 0) {
            uint4 u = HSq[(size_t)r * 16 + c];
            float2 p0 = bf2x2(u.x), p1 = bf2x2(u.y), p2 = bf2x2(u.z), p3 = bf2x2(u.w);
            a[0] += p0.x; a[1] += p0.y; a[2] += p1.x; a[3] += p1.y;
            a[4] += p2.x; a[5] += p2.y; a[6] += p3.x; a[7] += p3.y;
        }

        int e1 = end - 1;
        for (int j = beg; j < end; j += 16) {
            int i0 = j + jj, i1 = j + 4 + jj, i2 = j + 8 + jj, i3 = j + 12 + jj;
            int s0 = csr[min(i0, e1)];
            int s1 = csr[min(i1, e1)];
            int s2 = csr[min(i2, e1)];
            int s3 = csr[min(i3, e1)];
            uint4 v0 = HSq[(size_t)s0 * 16 + c];
            uint4 v1 = HSq[(size_t)s1 * 16 + c];
            uint4 v2 = HSq[(size_t)s2 * 16 + c];
            uint4 v3 = HSq[(size_t)s3 * 16 + c];
            if (i0 < end) {
                float2 p0 = bf2x2(v0.x), p1 = bf2x2(v0.y), p2 = bf2x2(v0.z), p3 = bf2x2(v0.w);
                a[0] += p0.x; a[1] += p0.y; a[2] += p1.x; a[3] += p1.y;
                a[4] += p2.x; a[5] += p2.y; a[6] += p3.x; a[7] += p3.y;
            }
            if (i1 < end) {
                float2 p0 = bf2x2(v1.x), p1 = bf2x2(v1.y), p2 = bf2x2(v1.z), p3 = bf2x2(v1.w);
                a[0] += p0.x; a[1] += p0.y; a[2] += p1.x; a[3] += p1.y;
                a[4] += p2.x; a[5] += p2.y; a[6] += p3.x; a[7] += p3.y;
            }
            if (i2 < end) {
                float2 p0 = bf2x2(v2.x), p1 = bf2x2(v2.y), p2 = bf2x2(v2.z), p3 = bf2x2(v2.w);
                a[0] += p0.x; a[1] += p0.y; a[2] += p1.x; a[3] += p1.y;
                a[4] += p2.x; a[5] += p2.y; a[6] += p3.x; a[7] += p3.y;
            }
            if (i3 < end) {
                float2 p0 = bf2x2(v3.x), p1 = bf2x2(v3.y), p2 = bf2x2(v3.z), p3 = bf2x2(v3.w);
                a[0] += p0.x; a[1] += p0.y; a[2] += p1.x; a[3] += p1.y;
                a[4] += p2.x; a[5] += p2.y; a[6] += p3.x; a[7] += p3.y;
            }
        }

#pragma unroll
        for (int t = 0; t < 8; ++t) {
            a[t] += __shfl_xor(a[t], 16);
            a[t] += __shfl_xor(a[t], 32);
        }

        if (jj == 0) {
            float dr = dis[r];
            float v[8];
            v[0] = fmaf(dr, a[0], bia0.x); v[1] = fmaf(dr, a[1], bia0.y);
            v[2] = fmaf(dr, a[2], bia0.z); v[3] = fmaf(dr, a[3], bia0.w);
            v[4] = fmaf(dr, a[4], bia1.x); v[5] = fmaf(dr, a[5], bia1.y);
            v[6] = fmaf(dr, a[6], bia1.z); v[7] = fmaf(dr, a[7], bia1.w);
            if (RELU) {
#pragma unroll
                for (int t = 0; t < 8; ++t) v[t] = fmaxf(v[t], 0.f);
            }
            float* op = OUT + (size_t)r * DD + c * 8;
            *(float4*)op       = make_float4(v[0], v[1], v[2], v[3]);
            *(float4*)(op + 4) = make_float4(v[4], v[5], v[6], v[7]);
#pragma unroll
            for (int t = 0; t < 8; ++t) { sum[t] += v[t]; sq[t] += v[t] * v[t]; }
        }
    }

    __shared__ float redS[4][16][8];
    __shared__ float redQ[4][16][8];
    if (jj == 0) {
#pragma unroll
        for (int t = 0; t < 8; ++t) { redS[wid][c][t] = sum[t]; redQ[wid][c][t] = sq[t]; }
    }
    __syncthreads();
    if (tid < 128) {
        int ci = tid >> 3, ct = tid & 7;
        float S = (redS[0][ci][ct] + redS[1][ci][ct]) + (redS[2][ci][ct] + redS[3][ci][ct]);
        float Q = (redQ[0][ci][ct] + redQ[1][ci][ct]) + (redQ[2][ci][ct] + redQ[3][ci][ct]);
        atomicAdd(&colsum[tid], S);
        atomicAdd(&colsumsq[tid], Q);
    }
}

extern "C" void kernel_launch(void* const* d_in, const int* in_sizes, int n_in,
                              void* d_out, int out_size, void* d_ws, size_t ws_size,
                              hipStream_t stream) {
    const float* x      = (const float*)d_in[0];
    const int*   ei     = (const int*)d_in[1];
    const float* conv_w = (const float*)d_in[2];
    const float* conv_b = (const float*)d_in[3];
    const float* bn_g   = (const float*)d_in[4];
    const float* bn_b   = (const float*)d_in[5];
    const float* mlp_w  = (const float*)d_in[6];
    const float* mlp_b  = (const float*)d_in[7];
    const float* out_w  = (const float*)d_in[8];
    const float* out_b  = (const float*)d_in[9];
    float* out = (float*)d_out;

    const size_t ND4 = (size_t)NN * DD * 4;   // 25,600,000 B
    char* ws = (char*)d_ws;
    size_t off = 0;
    float* B0      = (float*)(ws + off); off += ND4;            // fp32 features
    unsigned short* B1b = (unsigned short*)(ws + off); off += ND4 / 2;  // bf16 HS
    int*   deg     = (int*)  (ws + off); off += 204800;         // zeroed region start
    float* cs3     = (float*)(ws + off); off += 3 * 512;
    float* css3    = (float*)(ws + off); off += 3 * 512;        // zeroed region end
    float* dis     = (float*)(ws + off); off += 204800;
    int*   rowptr  = (int*)  (ws + off); off += 204804 + 60;
    int*   cursor  = (int*)  (ws + off); off += 204800;
    int*   bsum    = (int*)  (ws + off); off += 1024;
    unsigned short* Wfb = (unsigned short*)(ws + off); off += 5 * 16384 * 2;  // 160KB
    int*   csr     = (int*)  (ws + off); off += (size_t)EE * 4;
    // total ≈ 42.8 MB

    const int gemm_grid = (NN + 63) / 64;     // 782
    const int nscan = (NN + 255) / 256;       // 196
    const int gather_grid = 2048;             // 8192 waves

    hipMemsetAsync(deg, 0, 204800 + 6 * 512, stream);

    k_deg<<<(EE + 255) / 256, 256, 0, stream>>>(ei, deg);
    k_scan_block<<<nscan, 256, 0, stream>>>(deg, cursor, bsum);
    k_scan_final<<<nscan, 256, 0, stream>>>(deg, cursor, bsum, nscan, rowptr, cursor, dis);
    k_fill<<<(EE + 255) / 256, 256, 0, stream>>>(ei, cursor, csr);
    k_wprep<<<320, 256, 0, stream>>>(conv_w, mlp_w, Wfb);

    // ---- layer 0 ----
    k_gemm_conv<0><<<gemm_grid, 256, 0, stream>>>(x, Wfb, dis,
        nullptr, nullptr, nullptr, nullptr, B1b);
    k_gather<0><<<gather_grid, 256, 0, stream>>>(rowptr, csr, (const uint4*)B1b, dis, conv_b, B0, cs3, css3);

    // ---- layer 1 ----
    k_gemm_conv<1><<<gemm_grid, 256, 0, stream>>>(B0, Wfb + 16384, dis,
        cs3, css3, bn_g, bn_b, B1b);
    k_gather<0><<<gather_grid, 256, 0, stream>>>(rowptr, csr, (const uint4*)B1b, dis, conv_b + DD, B0, cs3 + 128, css3 + 128);

    // ---- layer 2 ----
    k_gemm_conv<1><<<gemm_grid, 256, 0, stream>>>(B0, Wfb + 2 * 16384, dis,
        cs3 + 128, css3 + 128, bn_g + DD, bn_b + DD, B1b);
    k_gather<1><<<gather_grid, 256, 0, stream>>>(rowptr, csr, (const uint4*)B1b, dis, conv_b + 2 * DD, B0, cs3 + 256, css3 + 256);

    // ---- fused MLP + head (BN stats 2, gamma/beta 1) ----
    k_mlp_head<<<gemm_grid, 256, 0, stream>>>(B0, Wfb + 3 * 16384, Wfb + 4 * 16384,
        mlp_b, mlp_b + DD, cs3 + 256, css3 + 256, bn_g + DD, bn_b + DD, out_w, out_b, out);
}